// Round 4
// baseline (210.732 us; speedup 1.0000x reference)
//
#include <hip/hip_runtime.h>
#include <stdint.h>

#define EPS 1e-5f

typedef short v8s __attribute__((ext_vector_type(8)));
typedef float v4f __attribute__((ext_vector_type(4)));

// ---------------- ws float layout ----------------
//  [0,4)     (unused)
//  16/80    c1 sum/ssq (64 each)
//  272/400  c2 sum/ssq (128 each)
//  1024  absmax partial c1 (1)
//  1025  absmax partial f2 (1)
//  1040  absmax partials c2 (192)
//  1240  absmax partials f1 (190)
//  1808 fc sum(512) 2320 fc ssq(512)
//  W2F  = 8192    : conv2 weights bf16 MFMA-frag order (204800 us)
//  WF2F = 212992  : fc2 weights float [j][512]
//  A_F  = 262144  : PMN1 packed uint [512][144][64] ([262144,4980736));
//                   later fc1out fp32 [512,512] ([262144,524288), PMN1 dead)
//  PMN2F= 4980736 : PMN2 fp32 [512][128][16][2] ([4980736,7077888))
//  B_F  = 19136512: xfrag bf16 B-frag [2048][512]
//  WF1T = B_F + 1048576 : fc1 weights bf16 A-frag
static const size_t W2F   = 8192;
static const size_t WF2F  = 212992;
static const size_t A_F   = 262144;
static const size_t PMN2F = 4980736;
static const size_t B_F   = 19136512;
static const size_t WF1T  = B_F + 1048576;

#define P_C1 1024
#define P_F2 1025
#define P_C2 1040
#define P_F1 1240

__device__ inline unsigned short f2bf(float f) {
    unsigned u = __float_as_uint(f);
    return (unsigned short)((u + 0x7FFF + ((u >> 16) & 1)) >> 16);
}

// async global->LDS, 16B per lane
__device__ __forceinline__ void stage16(const unsigned short* g, unsigned short* l) {
    __builtin_amdgcn_global_load_lds(
        (const __attribute__((address_space(1))) unsigned int*)g,
        (__attribute__((address_space(3))) unsigned int*)l, 16, 0, 0);
}

// absmax partials (plain stores, no atomics/zero needed) + zero stats sums.
// grid 390 x 256:
//   0: c1 -> wsf[P_C1]; 1: f2 -> wsf[P_F2];
//   2..193: c2 -> wsf[P_C2+bi] (192); 194..383: f1 -> wsf[P_F1+bi] (190);
//   384..385: zero [16,528);  386..389: zero [1808,2832)
__global__ void k_absz(const float* __restrict__ c1w, const float* __restrict__ c2w,
                       const float* __restrict__ f1w, const float* __restrict__ f2w,
                       float* __restrict__ wsf) {
    __shared__ float sm4[4];
    int blk = blockIdx.x;
    if (blk >= 384) {
        if (blk < 386) {
            int i = (blk - 384) * 256 + threadIdx.x + 16;
            if (i < 528) wsf[i] = 0.f;
        } else {
            int i = (blk - 386) * 256 + threadIdx.x + 1808;
            if (i < 2832) wsf[i] = 0.f;
        }
        return;
    }
    const float* w; int n; int nb; int bi; float* out;
    if (blk == 0)       { w = c1w; n = 1600;    nb = 1;   bi = 0;         out = wsf + P_C1; }
    else if (blk == 1)  { w = f2w; n = 5120;    nb = 1;   bi = 0;         out = wsf + P_F2; }
    else if (blk < 194) { w = c2w; n = 204800;  nb = 192; bi = blk - 2;   out = wsf + P_C2 + bi; }
    else                { w = f1w; n = 1048576; nb = 190; bi = blk - 194; out = wsf + P_F1 + bi; }
    float m = 0.f;
    for (int i = bi * 256 + threadIdx.x; i < n; i += nb * 256)
        m = fmaxf(m, fabsf(w[i]));
    #pragma unroll
    for (int o = 32; o; o >>= 1) m = fmaxf(m, __shfl_down(m, o));
    if ((threadIdx.x & 63) == 0) sm4[threadIdx.x >> 6] = m;
    __syncthreads();
    if (threadIdx.x == 0)
        *out = fmaxf(fmaxf(sm4[0], sm4[1]), fmaxf(sm4[2], sm4[3]));
}

// merged conv1 + ALL weight quant. grid 869 x 512:
//   [0,512)  : conv1 (inline conv1-weight quantize) -> PMN1 + bn1 stats
//   [512,612): conv2 bf16 A-frag quant (grid-stride)
//   [612,868): fc1 bf16 A-frag quant (grid-stride)
//   868      : fc2 float quant
__global__ __launch_bounds__(512) void k_mid(const float* __restrict__ x,
                                             const float* __restrict__ c1w,
                                             const float* __restrict__ c2w,
                                             const float* __restrict__ f1w,
                                             const float* __restrict__ f2w,
                                             float* __restrict__ wsf,
                                             unsigned* __restrict__ pmn1,
                                             unsigned short* __restrict__ w2u,
                                             unsigned short* __restrict__ wf1,
                                             float* __restrict__ wf2) {
    int blk = blockIdx.x;
    int tid = threadIdx.x;
    if (blk >= 512) {
        if (blk < 612) {
            // conv2 quant: threshold from 192 partials
            float m = 0.f;
            for (int i = 0; i < 192; ++i) m = fmaxf(m, wsf[P_C2 + i]);
            float t = 0.05f * m;
            for (int i = (blk - 512) * 512 + tid; i < 204800; i += 100 * 512) {
                int j    = i & 7;
                int lane = (i >> 3) & 63;
                int mt   = (i >> 9) & 7;
                int ks   = (i >> 12) & 1;
                int p    = i >> 13;
                int c  = mt * 16 + (lane & 15);
                int ci = ks * 32 + (lane >> 4) * 8 + j;
                float v = c2w[c * 1600 + ci * 25 + p];
                w2u[i] = (v > t) ? (unsigned short)0x3F80
                                 : ((v < -t) ? (unsigned short)0xBF80 : (unsigned short)0);
            }
        } else if (blk < 868) {
            // fc1 quant: threshold from 190 partials
            float m = 0.f;
            for (int i = 0; i < 190; ++i) m = fmaxf(m, wsf[P_F1 + i]);
            float t = 0.05f * m;
            for (int i = (blk - 612) * 512 + tid; i < 1048576; i += 256 * 512) {
                float v = f1w[i];
                unsigned short q = (v > t) ? (unsigned short)0x3F80
                                 : ((v < -t) ? (unsigned short)0xBF80 : (unsigned short)0);
                int f = i >> 11, k = i & 2047;
                int ft = f >> 4, fm = f & 15;
                int ks = k >> 5, kr = k & 31;
                int lane = (kr >> 3) * 16 + fm;
                wf1[((size_t)(ks * 32 + ft) * 64 + lane) * 8 + (kr & 7)] = q;
            }
        } else {
            float t = 0.05f * wsf[P_F2];
            for (int i = tid; i < 5120; i += 512) {
                float v = f2w[i];
                wf2[i] = (float)((v > t) - (v < -t));
            }
        }
        return;
    }
    // ---- conv1 ----
    __shared__ float xs[784];
    __shared__ float red[2][8][64];
    int b = blk;
    const float4* xim = (const float4*)(x + (size_t)b * 784);
    for (int i = tid; i < 196; i += 512) ((float4*)xs)[i] = xim[i];
    int c  = tid & 63;
    int wv = tid >> 6;
    float w[25];
    {
        float t = 0.05f * wsf[P_C1];
        const float* src = c1w + c * 25;
        #pragma unroll
        for (int k = 0; k < 25; ++k) {
            float v = src[k];
            w[k] = (float)((v > t) - (v < -t));
        }
    }
    __syncthreads();
    unsigned* ob = pmn1 + (size_t)b * 9216;
    float s = 0.f, s2 = 0.f;
    int ph = 0, pw = wv;
    for (int it = 0; it < 18; ++it) {
        const float* xp = xs + (ph * 2) * 28 + pw * 2;
        float win[36];
        #pragma unroll
        for (int i = 0; i < 6; ++i)
            #pragma unroll
            for (int j = 0; j < 3; ++j) {
                float2 t2 = *(const float2*)(xp + i * 28 + j * 2);
                win[i * 6 + j * 2] = t2.x; win[i * 6 + j * 2 + 1] = t2.y;
            }
        float v00 = 0.f, v01 = 0.f, v10 = 0.f, v11 = 0.f;
        #pragma unroll
        for (int i = 0; i < 5; ++i)
            #pragma unroll
            for (int j = 0; j < 5; ++j) {
                float wk = w[i * 5 + j];
                v00 = fmaf(win[i * 6 + j],           wk, v00);
                v01 = fmaf(win[i * 6 + j + 1],       wk, v01);
                v10 = fmaf(win[(i + 1) * 6 + j],     wk, v10);
                v11 = fmaf(win[(i + 1) * 6 + j + 1], wk, v11);
            }
        s  += v00 + v01 + v10 + v11;
        s2 += v00 * v00 + v01 * v01 + v10 * v10 + v11 * v11;
        float mx = fmaxf(fmaxf(v00, v01), fmaxf(v10, v11));
        float mn = fminf(fminf(v00, v01), fminf(v10, v11));
        ob[(ph * 12 + pw) * 64 + c] = ((unsigned)f2bf(mx) << 16) | (unsigned)f2bf(mn);
        pw += 8; if (pw >= 12) { pw -= 12; ++ph; }
    }
    red[0][wv][c] = s; red[1][wv][c] = s2;
    __syncthreads();
    if (tid < 64) {
        float S = 0.f, S2 = 0.f;
        #pragma unroll
        for (int i = 0; i < 8; ++i) { S += red[0][i][tid]; S2 += red[1][i][tid]; }
        atomicAdd(&wsf[16 + tid], S);
        atomicAdd(&wsf[80 + tid], S2);
    }
}

// conv2 MFMA with fused bn1-finalize staging. Inner loop v2: strength-reduced
// addressing (incremental pointers) + p-loop unrolled by 2 (compile-time buf).
__global__ __launch_bounds__(256) void k_conv2(const unsigned* __restrict__ pmn1,
                                               const unsigned short* __restrict__ wfrag,
                                               const float* __restrict__ c1sum,
                                               const float* __restrict__ c1ssq,
                                               const float* __restrict__ g1,
                                               const float* __restrict__ b1,
                                               float* __restrict__ pmn,
                                               float* __restrict__ sum,
                                               float* __restrict__ ssq) {
    __shared__ unsigned short xs[144 * 76];    // 21888 B; reused as merge buf
    __shared__ unsigned short wb[2][4096];     // 2 x 8KB: one p = 2 ks x 4 mt
    __shared__ float reds[2][64], redq[2][64];
    int b     = blockIdx.x >> 1;
    int mhalf = blockIdx.x & 1;
    int tid  = threadIdx.x;
    int lane = tid & 63;
    int wave = tid >> 6;
    int nh = wave & 1, kp = wave >> 1;

    // bn1 finalize params for this thread's 4 fixed channels
    int ch0 = (tid & 15) * 4;
    float scv[4], shv[4];
    {
        const float invN = 1.f / 294912.f;
        #pragma unroll
        for (int j = 0; j < 4; ++j) {
            int ch = ch0 + j;
            float mean = c1sum[ch] * invN;
            float var  = c1ssq[ch] * invN - mean * mean;
            scv[j] = g1[ch] * rsqrtf(var + EPS);
            shv[j] = b1[ch] - mean * scv[j];
        }
    }
    // fused staging: PMN1 [144][64] packed -> bn1+relu+select -> xs bf16
    const uint4* srcp = (const uint4*)(pmn1 + (size_t)b * 9216);
    for (int it = 0; it < 9; ++it) {
        int i = it * 256 + tid;                // uint4 index, 2304 total
        int r = i >> 4;                        // row 0..143 (ch-group = tid&15)
        uint4 u4 = srcp[i];
        unsigned long long pack = 0;
        #pragma unroll
        for (int j = 0; j < 4; ++j) {
            unsigned u = (&u4.x)[j];
            float mx = __uint_as_float(u & 0xffff0000u);
            float mn = __uint_as_float(u << 16);
            float v = (scv[j] > 0.f) ? mx : mn;
            unsigned short o = f2bf(fmaxf(0.f, fmaf(v, scv[j], shv[j])));
            pack |= ((unsigned long long)o) << (16 * j);
        }
        *(unsigned long long*)(&xs[r * 76 + ch0]) = pack;
    }
    // precomputed staging pointers (increment by 8192 elems = one p-step)
    int ksm0 = wave * 2, ksm1 = wave * 2 + 1;
    int ks0 = ksm0 >> 2, mt0 = ksm0 & 3;
    int ks1 = ksm1 >> 2, mt1 = ksm1 & 3;
    const unsigned short* g0 = wfrag + (size_t)(ks0 * 8 + mhalf * 4 + mt0) * 512 + lane * 8;
    const unsigned short* g1p = wfrag + (size_t)(ks1 * 8 + mhalf * 4 + mt1) * 512 + lane * 8;
    const int l0 = ks0 * 2048 + mt0 * 512 + lane * 8;
    const int l1 = ks1 * 2048 + mt1 * 512 + lane * 8;
    // prefetch p=0 weights
    stage16(g0,  &wb[0][l0]);
    stage16(g1p, &wb[0][l1]);
    g0 += 8192; g1p += 8192;
    __syncthreads();

    int n = lane & 15, quad = lane >> 4;
    int ow = n & 7;
    int ohb0 = nh * 4 + (n >> 3);              // oh of bf0; bf1 = +2
    int col0 = kp * 32 + quad * 8;
    const int lb = kp * 2048 + lane * 8;
    int a0 = ohb0 * 912 + ow * 76 + col0;      // xs read addr (shorts), p=0
    int kw = 0;
    v4f acc[4][2];
    #pragma unroll
    for (int mm = 0; mm < 4; ++mm) { acc[mm][0] = (v4f){0,0,0,0}; acc[mm][1] = (v4f){0,0,0,0}; }

    auto step = [&](const unsigned short* wbR, unsigned short* wbW, bool st) {
        if (st) {
            stage16(g0,  wbW + l0);
            stage16(g1p, wbW + l1);
            g0 += 8192; g1p += 8192;
        }
        v8s bf0 = *(const v8s*)(xs + a0);
        v8s bf1 = *(const v8s*)(xs + a0 + 1824);
        #pragma unroll
        for (int mm = 0; mm < 4; ++mm) {
            v8s af = *(const v8s*)(wbR + lb + mm * 512);
            acc[mm][0] = __builtin_amdgcn_mfma_f32_16x16x32_bf16(af, bf0, acc[mm][0], 0, 0, 0);
            acc[mm][1] = __builtin_amdgcn_mfma_f32_16x16x32_bf16(af, bf1, acc[mm][1], 0, 0, 0);
        }
        __syncthreads();
        a0 += (kw == 4) ? 608 : 76;
        kw = (kw == 4) ? 0 : kw + 1;
    };
    #pragma unroll 1
    for (int pp = 0; pp < 12; ++pp) {
        step(&wb[0][0], &wb[1][0], true);      // even p: read buf0, stage buf1
        step(&wb[1][0], &wb[0][0], true);      // odd p:  read buf1, stage buf0
    }
    step(&wb[0][0], &wb[1][0], false);         // p = 24

    // merge kp=1 partials into kp=0 via dead act-LDS (stride-36 float pad)
    float* mbuf = (float*)xs;                  // 128*36*4 = 18432 B <= 21888
    if (kp == 1) {
        float* d = mbuf + (nh * 64 + lane) * 36;
        #pragma unroll
        for (int mm = 0; mm < 4; ++mm) {
            *(v4f*)(d + mm * 8)     = acc[mm][0];
            *(v4f*)(d + mm * 8 + 4) = acc[mm][1];
        }
    }
    __syncthreads();
    if (kp == 0) {
        const float* s = mbuf + (nh * 64 + lane) * 36;
        #pragma unroll
        for (int mm = 0; mm < 4; ++mm) {
            acc[mm][0] += *(const v4f*)(s + mm * 8);
            acc[mm][1] += *(const v4f*)(s + mm * 8 + 4);
        }
        // epilogue: pooled {max,min} + per-channel stats (64 ch within block)
        float* po = pmn + (size_t)b * 4096;    // [128][16][2]
        #pragma unroll
        for (int mm = 0; mm < 4; ++mm) {
            int cl0 = mm * 16 + quad * 4;
            #pragma unroll
            for (int r = 0; r < 4; ++r) {
                int cl = cl0 + r;
                int cc = mhalf * 64 + cl;
                float sA = 0.f, s2A = 0.f;
                #pragma unroll
                for (int bf = 0; bf < 2; ++bf) {
                    float v = acc[mm][bf][r];
                    float pm = fmaxf(v, __shfl_xor(v, 1));
                    float pn = fminf(v, __shfl_xor(v, 1));
                    pm = fmaxf(pm, __shfl_xor(pm, 8));
                    pn = fminf(pn, __shfl_xor(pn, 8));
                    if (((n & 1) == 0) && (n < 8)) {
                        int psp = (nh * 2 + bf) * 4 + (n >> 1);
                        *(float2*)(&po[(cc * 16 + psp) * 2]) = make_float2(pm, pn);
                    }
                    float s = v, s2 = v * v;
                    #pragma unroll
                    for (int m = 1; m < 16; m <<= 1) { s += __shfl_xor(s, m); s2 += __shfl_xor(s2, m); }
                    sA += s; s2A += s2;
                }
                if (n == 0) { reds[nh][cl] = sA; redq[nh][cl] = s2A; }
            }
        }
    }
    __syncthreads();
    if (tid < 64) {
        atomicAdd(&sum[mhalf * 64 + tid], reds[0][tid] + reds[1][tid]);
        atomicAdd(&ssq[mhalf * 64 + tid], redq[0][tid] + redq[1][tid]);
    }
}

// bnpool2 only (fc1 quant moved into k_mid): PMN2 -> bn2+relu+pool -> xfrag
__global__ void k_bnpool2(const float* __restrict__ pmn2, const float* __restrict__ c2sum,
                          const float* __restrict__ c2ssq, const float* __restrict__ g2,
                          const float* __restrict__ b2, unsigned short* __restrict__ xfrag) {
    int i = blockIdx.x * 256 + threadIdx.x;    // 1048576
    int j    = i & 7;
    int lane = (i >> 3) & 63;
    int bt   = (i >> 9) & 31;
    int ks   = i >> 14;
    int b = bt * 16 + (lane & 15);
    int k = ks * 32 + (lane >> 4) * 8 + j;
    int c = k >> 4, psp = k & 15;
    float2 mm = *(const float2*)(&pmn2[((size_t)b * 2048 + c * 16 + psp) * 2]);
    float mean = c2sum[c] * (1.f / 32768.f);
    float var  = c2ssq[c] * (1.f / 32768.f) - mean * mean;
    float sc = g2[c] * rsqrtf(var + EPS);
    float sh = b2[c] - mean * sc;
    float v = (sc > 0.f) ? mm.x : mm.y;
    xfrag[i] = f2bf(fmaxf(0.f, fmaf(v, sc, sh)));
}

// fc1 MFMA: grid 256, wave = 1 f-tile; fused bn3 stats.
__global__ __launch_bounds__(256) void k_fc1(const unsigned short* __restrict__ xfrag,
                                             const unsigned short* __restrict__ wfrag,
                                             float* __restrict__ out,
                                             float* __restrict__ sum,
                                             float* __restrict__ ssq) {
    int lane = threadIdx.x & 63;
    int wave = threadIdx.x >> 6;
    int ft = (blockIdx.x & 7) * 4 + wave;      // f-tile 0..31
    int bT = blockIdx.x >> 3;                  // 0..31
    v4f acc = (v4f){0.f, 0.f, 0.f, 0.f};
    for (int ks = 0; ks < 64; ++ks) {
        v8s bfrag = *(const v8s*)(xfrag + ((size_t)(ks * 32 + bT) * 64 + lane) * 8);
        v8s afrag = *(const v8s*)(wfrag + ((size_t)(ks * 32 + ft) * 64 + lane) * 8);
        acc = __builtin_amdgcn_mfma_f32_16x16x32_bf16(afrag, bfrag, acc, 0, 0, 0);
    }
    int bb = bT * 16 + (lane & 15);
    int quad = lane >> 4;
    int f0 = ft * 16 + quad * 4;
    *(float4*)(&out[(size_t)bb * 512 + f0]) =
        make_float4(acc[0], acc[1], acc[2], acc[3]);
    #pragma unroll
    for (int r = 0; r < 4; ++r) {
        float s = acc[r], s2 = s * s;
        #pragma unroll
        for (int m = 1; m < 16; m <<= 1) { s += __shfl_xor(s, m); s2 += __shfl_xor(s2, m); }
        if ((lane & 15) == 0) { atomicAdd(&sum[f0 + r], s); atomicAdd(&ssq[f0 + r], s2); }
    }
}

// fc2 with inline bn3 finalize + relu: wave per batch row.
__global__ __launch_bounds__(256) void k_fc2(const float* __restrict__ x,
                                             const float* __restrict__ w,
                                             const float* __restrict__ bias,
                                             const float* __restrict__ fsum,
                                             const float* __restrict__ fssq,
                                             const float* __restrict__ g3,
                                             const float* __restrict__ b3,
                                             float* __restrict__ out) {
    int lane = threadIdx.x & 63;
    int b = blockIdx.x * 4 + (threadIdx.x >> 6);
    float xa[8], sm[8], sq[8], ga[8], ba[8];
    {
        const float4* p;
        p = (const float4*)(x + (size_t)b * 512 + lane * 8);
        *(float4*)xa = p[0]; *(float4*)(xa + 4) = p[1];
        p = (const float4*)(fsum + lane * 8);
        *(float4*)sm = p[0]; *(float4*)(sm + 4) = p[1];
        p = (const float4*)(fssq + lane * 8);
        *(float4*)sq = p[0]; *(float4*)(sq + 4) = p[1];
        p = (const float4*)(g3 + lane * 8);
        *(float4*)ga = p[0]; *(float4*)(ga + 4) = p[1];
        p = (const float4*)(b3 + lane * 8);
        *(float4*)ba = p[0]; *(float4*)(ba + 4) = p[1];
    }
    float h[8];
    #pragma unroll
    for (int e = 0; e < 8; ++e) {
        float mean = sm[e] * (1.f / 512.f);
        float var  = sq[e] * (1.f / 512.f) - mean * mean;
        float sc = ga[e] * rsqrtf(var + EPS);
        float sh = ba[e] - mean * sc;
        h[e] = fmaxf(0.f, fmaf(xa[e], sc, sh));
    }
    #pragma unroll
    for (int j = 0; j < 10; ++j) {
        const float4* wp = (const float4*)(w + j * 512 + lane * 8);
        float4 w0 = wp[0], w1 = wp[1];
        float p = h[0] * w0.x + h[1] * w0.y + h[2] * w0.z + h[3] * w0.w
                + h[4] * w1.x + h[5] * w1.y + h[6] * w1.z + h[7] * w1.w;
        #pragma unroll
        for (int o = 32; o; o >>= 1) p += __shfl_down(p, o);
        if (lane == 0) out[b * 10 + j] = p + bias[j];
    }
}

extern "C" void kernel_launch(void* const* d_in, const int* in_sizes, int n_in,
                              void* d_out, int out_size, void* d_ws, size_t ws_size,
                              hipStream_t stream) {
    const float* x       = (const float*)d_in[0];
    const float* conv1_w = (const float*)d_in[1];
    const float* bn1_g   = (const float*)d_in[3];
    const float* bn1_b   = (const float*)d_in[4];
    const float* conv2_w = (const float*)d_in[5];
    const float* bn2_g   = (const float*)d_in[7];
    const float* bn2_b   = (const float*)d_in[8];
    const float* fc1_w   = (const float*)d_in[9];
    const float* bn3_g   = (const float*)d_in[11];
    const float* bn3_b   = (const float*)d_in[12];
    const float* fc2_w   = (const float*)d_in[13];
    const float* fc2_b   = (const float*)d_in[14];
    // conv1_b / conv2_b / fc1_b are absorbed by train-mode BN

    float* wsf = (float*)d_ws;

    float* c1_sum = wsf + 16,   * c1_ssq = wsf + 80;
    float* c2_sum = wsf + 272,  * c2_ssq = wsf + 400;
    float* f_sum  = wsf + 1808, * f_ssq  = wsf + 2320;

    unsigned short* w2u = (unsigned short*)(wsf + W2F);
    float* wf2 = wsf + WF2F;
    unsigned short* wf1 = (unsigned short*)(wsf + WF1T);
    unsigned* PMN1 = (unsigned*)(wsf + A_F);         // [512][144][64] packed
    float* PMN2 = wsf + PMN2F;                       // [512][128][16][2]
    float* A    = wsf + A_F;                         // fc1out (PMN1 dead by then)
    unsigned short* xfrag = (unsigned short*)(wsf + B_F);

    // absmax partials + zero stats sums — one launch
    k_absz<<<390, 256, 0, stream>>>(conv1_w, conv2_w, fc1_w, fc2_w, wsf);

    // conv1 (inline c1 quant) + conv2/fc1/fc2 quant — one launch
    k_mid<<<869, 512, 0, stream>>>(x, conv1_w, conv2_w, fc1_w, fc2_w, wsf,
                                   PMN1, w2u, wf1, wf2);

    // conv2 MFMA with fused bn1-finalize staging, strength-reduced loop
    k_conv2<<<1024, 256, 0, stream>>>(PMN1, w2u, c1_sum, c1_ssq, bn1_g, bn1_b,
                                      PMN2, c2_sum, c2_ssq);

    // bnpool2 -> xfrag
    k_bnpool2<<<4096, 256, 0, stream>>>(PMN2, c2_sum, c2_ssq, bn2_g, bn2_b, xfrag);

    // fc1 MFMA (grid 256, fused bn3 stats) -> A fp32 [512,512]
    k_fc1<<<256, 256, 0, stream>>>(xfrag, wf1, A, f_sum, f_ssq);

    // fc2 (inline bn3 finalize + relu) -> d_out [512,10]
    k_fc2<<<128, 256, 0, stream>>>(A, wf2, fc2_b, f_sum, f_ssq, bn3_g, bn3_b,
                                   (float*)d_out);
}

// Round 5
// 208.493 us; speedup vs baseline: 1.0107x; 1.0107x over previous
//
#include <hip/hip_runtime.h>
#include <stdint.h>

#define EPS 1e-5f

typedef short v8s __attribute__((ext_vector_type(8)));
typedef float v4f __attribute__((ext_vector_type(4)));

// ---------------- ws float layout ----------------
//  16/80    c1 sum/ssq (64 each)
//  272/400  c2 sum/ssq (128 each)
//  1024  absmax partial c1 (1)
//  1025  absmax partial f2 (1)
//  1040  absmax partials c2 (192)
//  1240  absmax partials f1 (190)
//  1808 fc sum(512) 2320 fc ssq(512)
//  W2F  = 8192    : conv2 weights bf16 MFMA-frag order (204800 us)
//  WF2F = 212992  : fc2 weights float [j][512]
//  A_F  = 262144  : PMN1 packed uint [512][144][64] ([262144,4980736));
//                   later fc1out fp32 [512,512] ([262144,524288), PMN1 dead)
//  PMN2F= 4980736 : PMN2 fp32 [512][128][16][2]
//  B_F  = 19136512: xfrag bf16 B-frag [2048][512]
//  WF1T = B_F + 1048576 : fc1 weights bf16 A-frag
static const size_t W2F   = 8192;
static const size_t WF2F  = 212992;
static const size_t A_F   = 262144;
static const size_t PMN2F = 4980736;
static const size_t B_F   = 19136512;
static const size_t WF1T  = B_F + 1048576;

#define P_C1 1024
#define P_F2 1025
#define P_C2 1040
#define P_F1 1240

__device__ inline unsigned short f2bf(float f) {
    unsigned u = __float_as_uint(f);
    return (unsigned short)((u + 0x7FFF + ((u >> 16) & 1)) >> 16);
}

// async global->LDS, 16B per lane
__device__ __forceinline__ void stage16(const unsigned short* g, unsigned short* l) {
    __builtin_amdgcn_global_load_lds(
        (const __attribute__((address_space(1))) unsigned int*)g,
        (__attribute__((address_space(3))) unsigned int*)l, 16, 0, 0);
}

// absmax partials (plain stores) + zero stats sums. grid 390 x 256.
__global__ void k_absz(const float* __restrict__ c1w, const float* __restrict__ c2w,
                       const float* __restrict__ f1w, const float* __restrict__ f2w,
                       float* __restrict__ wsf) {
    __shared__ float sm4[4];
    int blk = blockIdx.x;
    if (blk >= 384) {
        if (blk < 386) {
            int i = (blk - 384) * 256 + threadIdx.x + 16;
            if (i < 528) wsf[i] = 0.f;
        } else {
            int i = (blk - 386) * 256 + threadIdx.x + 1808;
            if (i < 2832) wsf[i] = 0.f;
        }
        return;
    }
    const float* w; int n; int nb; int bi; float* out;
    if (blk == 0)       { w = c1w; n = 1600;    nb = 1;   bi = 0;         out = wsf + P_C1; }
    else if (blk == 1)  { w = f2w; n = 5120;    nb = 1;   bi = 0;         out = wsf + P_F2; }
    else if (blk < 194) { w = c2w; n = 204800;  nb = 192; bi = blk - 2;   out = wsf + P_C2 + bi; }
    else                { w = f1w; n = 1048576; nb = 190; bi = blk - 194; out = wsf + P_F1 + bi; }
    float m = 0.f;
    for (int i = bi * 256 + threadIdx.x; i < n; i += nb * 256)
        m = fmaxf(m, fabsf(w[i]));
    #pragma unroll
    for (int o = 32; o; o >>= 1) m = fmaxf(m, __shfl_down(m, o));
    if ((threadIdx.x & 63) == 0) sm4[threadIdx.x >> 6] = m;
    __syncthreads();
    if (threadIdx.x == 0)
        *out = fmaxf(fmaxf(sm4[0], sm4[1]), fmaxf(sm4[2], sm4[3]));
}

// merged conv1 + ALL weight quant. grid 869 x 512.
__global__ __launch_bounds__(512) void k_mid(const float* __restrict__ x,
                                             const float* __restrict__ c1w,
                                             const float* __restrict__ c2w,
                                             const float* __restrict__ f1w,
                                             const float* __restrict__ f2w,
                                             float* __restrict__ wsf,
                                             unsigned* __restrict__ pmn1,
                                             unsigned short* __restrict__ w2u,
                                             unsigned short* __restrict__ wf1,
                                             float* __restrict__ wf2) {
    int blk = blockIdx.x;
    int tid = threadIdx.x;
    if (blk >= 512) {
        if (blk < 612) {
            float m = 0.f;
            for (int i = 0; i < 192; ++i) m = fmaxf(m, wsf[P_C2 + i]);
            float t = 0.05f * m;
            for (int i = (blk - 512) * 512 + tid; i < 204800; i += 100 * 512) {
                int j    = i & 7;
                int lane = (i >> 3) & 63;
                int mt   = (i >> 9) & 7;
                int ks   = (i >> 12) & 1;
                int p    = i >> 13;
                int c  = mt * 16 + (lane & 15);
                int ci = ks * 32 + (lane >> 4) * 8 + j;
                float v = c2w[c * 1600 + ci * 25 + p];
                w2u[i] = (v > t) ? (unsigned short)0x3F80
                                 : ((v < -t) ? (unsigned short)0xBF80 : (unsigned short)0);
            }
        } else if (blk < 868) {
            float m = 0.f;
            for (int i = 0; i < 190; ++i) m = fmaxf(m, wsf[P_F1 + i]);
            float t = 0.05f * m;
            for (int i = (blk - 612) * 512 + tid; i < 1048576; i += 256 * 512) {
                float v = f1w[i];
                unsigned short q = (v > t) ? (unsigned short)0x3F80
                                 : ((v < -t) ? (unsigned short)0xBF80 : (unsigned short)0);
                int f = i >> 11, k = i & 2047;
                int ft = f >> 4, fm = f & 15;
                int ks = k >> 5, kr = k & 31;
                int lane = (kr >> 3) * 16 + fm;
                wf1[((size_t)(ks * 32 + ft) * 64 + lane) * 8 + (kr & 7)] = q;
            }
        } else {
            float t = 0.05f * wsf[P_F2];
            for (int i = tid; i < 5120; i += 512) {
                float v = f2w[i];
                wf2[i] = (float)((v > t) - (v < -t));
            }
        }
        return;
    }
    // ---- conv1 ----
    __shared__ float xs[784];
    __shared__ float red[2][8][64];
    int b = blk;
    const float4* xim = (const float4*)(x + (size_t)b * 784);
    for (int i = tid; i < 196; i += 512) ((float4*)xs)[i] = xim[i];
    int c  = tid & 63;
    int wv = tid >> 6;
    float w[25];
    {
        float t = 0.05f * wsf[P_C1];
        const float* src = c1w + c * 25;
        #pragma unroll
        for (int k = 0; k < 25; ++k) {
            float v = src[k];
            w[k] = (float)((v > t) - (v < -t));
        }
    }
    __syncthreads();
    unsigned* ob = pmn1 + (size_t)b * 9216;
    float s = 0.f, s2 = 0.f;
    int ph = 0, pw = wv;
    for (int it = 0; it < 18; ++it) {
        const float* xp = xs + (ph * 2) * 28 + pw * 2;
        float win[36];
        #pragma unroll
        for (int i = 0; i < 6; ++i)
            #pragma unroll
            for (int j = 0; j < 3; ++j) {
                float2 t2 = *(const float2*)(xp + i * 28 + j * 2);
                win[i * 6 + j * 2] = t2.x; win[i * 6 + j * 2 + 1] = t2.y;
            }
        float v00 = 0.f, v01 = 0.f, v10 = 0.f, v11 = 0.f;
        #pragma unroll
        for (int i = 0; i < 5; ++i)
            #pragma unroll
            for (int j = 0; j < 5; ++j) {
                float wk = w[i * 5 + j];
                v00 = fmaf(win[i * 6 + j],           wk, v00);
                v01 = fmaf(win[i * 6 + j + 1],       wk, v01);
                v10 = fmaf(win[(i + 1) * 6 + j],     wk, v10);
                v11 = fmaf(win[(i + 1) * 6 + j + 1], wk, v11);
            }
        s  += v00 + v01 + v10 + v11;
        s2 += v00 * v00 + v01 * v01 + v10 * v10 + v11 * v11;
        float mx = fmaxf(fmaxf(v00, v01), fmaxf(v10, v11));
        float mn = fminf(fminf(v00, v01), fminf(v10, v11));
        ob[(ph * 12 + pw) * 64 + c] = ((unsigned)f2bf(mx) << 16) | (unsigned)f2bf(mn);
        pw += 8; if (pw >= 12) { pw -= 12; ++ph; }
    }
    red[0][wv][c] = s; red[1][wv][c] = s2;
    __syncthreads();
    if (tid < 64) {
        float S = 0.f, S2 = 0.f;
        #pragma unroll
        for (int i = 0; i < 8; ++i) { S += red[0][i][tid]; S2 += red[1][i][tid]; }
        atomicAdd(&wsf[16 + tid], S);
        atomicAdd(&wsf[80 + tid], S2);
    }
}

// conv2 MFMA: r3-exact addressing/compute, NEW sync schedule — 3-buffer
// weight ring, prefetch distance 2, counted s_waitcnt vmcnt(2) (never 0 in
// steady state), two raw s_barriers per step (T3/T4 pattern).
__global__ __launch_bounds__(256) void k_conv2(const unsigned* __restrict__ pmn1,
                                               const unsigned short* __restrict__ wfrag,
                                               const float* __restrict__ c1sum,
                                               const float* __restrict__ c1ssq,
                                               const float* __restrict__ g1,
                                               const float* __restrict__ b1,
                                               float* __restrict__ pmn,
                                               float* __restrict__ sum,
                                               float* __restrict__ ssq) {
    __shared__ unsigned short xs[144 * 76];    // 21888 B; reused as merge buf
    __shared__ unsigned short wb[3][4096];     // 3 x 8KB ring: one p = 2 ks x 4 mt
    __shared__ float reds[2][64], redq[2][64];
    int b     = blockIdx.x >> 1;
    int mhalf = blockIdx.x & 1;
    int tid  = threadIdx.x;
    int lane = tid & 63;
    int wave = tid >> 6;
    int nh = wave & 1, kp = wave >> 1;

    // bn1 finalize params for this thread's 4 fixed channels
    int ch0 = (tid & 15) * 4;
    float scv[4], shv[4];
    {
        const float invN = 1.f / 294912.f;
        #pragma unroll
        for (int j = 0; j < 4; ++j) {
            int ch = ch0 + j;
            float mean = c1sum[ch] * invN;
            float var  = c1ssq[ch] * invN - mean * mean;
            scv[j] = g1[ch] * rsqrtf(var + EPS);
            shv[j] = b1[ch] - mean * scv[j];
        }
    }
    // fused staging: PMN1 [144][64] packed -> bn1+relu+select -> xs bf16
    const uint4* srcp = (const uint4*)(pmn1 + (size_t)b * 9216);
    for (int it = 0; it < 9; ++it) {
        int i = it * 256 + tid;                // uint4 index, 2304 total
        int r = i >> 4;                        // row 0..143 (ch-group = tid&15)
        uint4 u4 = srcp[i];
        unsigned long long pack = 0;
        #pragma unroll
        for (int j = 0; j < 4; ++j) {
            unsigned u = (&u4.x)[j];
            float mx = __uint_as_float(u & 0xffff0000u);
            float mn = __uint_as_float(u << 16);
            float v = (scv[j] > 0.f) ? mx : mn;
            unsigned short o = f2bf(fmaxf(0.f, fmaf(v, scv[j], shv[j])));
            pack |= ((unsigned long long)o) << (16 * j);
        }
        *(unsigned long long*)(&xs[r * 76 + ch0]) = pack;
    }
    // prefetch p=0 and p=1 weights (distance-2 pipeline prologue)
    #pragma unroll
    for (int pp = 0; pp < 2; ++pp) {
        #pragma unroll
        for (int h = 0; h < 2; ++h) {
            int ksm = wave * 2 + h;
            int ks = ksm >> 2, mt = ksm & 3;
            const unsigned short* g = wfrag +
                (size_t)((pp * 2 + ks) * 8 + mhalf * 4 + mt) * 512 + lane * 8;
            stage16(g, &wb[pp][ks * 2048 + mt * 512 + lane * 8]);
        }
    }
    __syncthreads();   // one-time full drain: xs writes + stage(0),stage(1)

    int n = lane & 15, quad = lane >> 4;
    int ow = n & 7;
    int ohb0 = nh * 4 + (n >> 3);              // oh of bf0; bf1 = +2
    int col0 = kp * 32 + quad * 8;
    v4f acc[4][2];
    #pragma unroll
    for (int mm = 0; mm < 4; ++mm) { acc[mm][0] = (v4f){0,0,0,0}; acc[mm][1] = (v4f){0,0,0,0}; }
    for (int p = 0; p < 25; ++p) {
        int cur = p % 3;
        int kh = p / 5, kw = p - (p / 5) * 5;
        int col = (ow + kw) * 76 + col0;
        v8s bf0 = *(const v8s*)(&xs[(ohb0 + kh) * 912 + col]);       // 12*76=912
        v8s bf1 = *(const v8s*)(&xs[(ohb0 + 2 + kh) * 912 + col]);
        #pragma unroll
        for (int mm = 0; mm < 4; ++mm) {
            v8s af = *(const v8s*)(&wb[cur][kp * 2048 + mm * 512 + lane * 8]);
            acc[mm][0] = __builtin_amdgcn_mfma_f32_16x16x32_bf16(af, bf0, acc[mm][0], 0, 0, 0);
            acc[mm][1] = __builtin_amdgcn_mfma_f32_16x16x32_bf16(af, bf1, acc[mm][1], 0, 0, 0);
        }
        // B2: all waves done reading wb[cur] and xs for step p
        asm volatile("s_barrier" ::: "memory");
        if (p <= 22) {
            int pn = p + 2, nxt = pn % 3;      // overwrites buf last read at p-1
            #pragma unroll
            for (int h = 0; h < 2; ++h) {
                int ksm = wave * 2 + h;
                int ks = ksm >> 2, mt = ksm & 3;
                const unsigned short* g = wfrag +
                    (size_t)((pn * 2 + ks) * 8 + mhalf * 4 + mt) * 512 + lane * 8;
                stage16(g, &wb[nxt][ks * 2048 + mt * 512 + lane * 8]);
            }
            // wait for stage(p+1) only; stage(p+2) stays in flight
            asm volatile("s_waitcnt vmcnt(2)" ::: "memory");
        } else if (p == 23) {
            asm volatile("s_waitcnt vmcnt(0)" ::: "memory");
        }
        if (p <= 23)
            asm volatile("s_barrier" ::: "memory");   // B1: stage(p+1) visible
    }
    // merge kp=1 partials into kp=0 via dead act-LDS (stride-36 float pad)
    float* mbuf = (float*)xs;                  // 128*36*4 = 18432 B <= 21888
    if (kp == 1) {
        float* d = mbuf + (nh * 64 + lane) * 36;
        #pragma unroll
        for (int mm = 0; mm < 4; ++mm) {
            *(v4f*)(d + mm * 8)     = acc[mm][0];
            *(v4f*)(d + mm * 8 + 4) = acc[mm][1];
        }
    }
    __syncthreads();
    if (kp == 0) {
        const float* s = mbuf + (nh * 64 + lane) * 36;
        #pragma unroll
        for (int mm = 0; mm < 4; ++mm) {
            acc[mm][0] += *(const v4f*)(s + mm * 8);
            acc[mm][1] += *(const v4f*)(s + mm * 8 + 4);
        }
        // epilogue: pooled {max,min} + per-channel stats (64 ch within block)
        float* po = pmn + (size_t)b * 4096;    // [128][16][2]
        #pragma unroll
        for (int mm = 0; mm < 4; ++mm) {
            int cl0 = mm * 16 + quad * 4;
            #pragma unroll
            for (int r = 0; r < 4; ++r) {
                int cl = cl0 + r;
                int cc = mhalf * 64 + cl;
                float sA = 0.f, s2A = 0.f;
                #pragma unroll
                for (int bf = 0; bf < 2; ++bf) {
                    float v = acc[mm][bf][r];
                    float pm = fmaxf(v, __shfl_xor(v, 1));
                    float pn = fminf(v, __shfl_xor(v, 1));
                    pm = fmaxf(pm, __shfl_xor(pm, 8));
                    pn = fminf(pn, __shfl_xor(pn, 8));
                    if (((n & 1) == 0) && (n < 8)) {
                        int psp = (nh * 2 + bf) * 4 + (n >> 1);
                        *(float2*)(&po[(cc * 16 + psp) * 2]) = make_float2(pm, pn);
                    }
                    float s = v, s2 = v * v;
                    #pragma unroll
                    for (int m = 1; m < 16; m <<= 1) { s += __shfl_xor(s, m); s2 += __shfl_xor(s2, m); }
                    sA += s; s2A += s2;
                }
                if (n == 0) { reds[nh][cl] = sA; redq[nh][cl] = s2A; }
            }
        }
    }
    __syncthreads();
    if (tid < 64) {
        atomicAdd(&sum[mhalf * 64 + tid], reds[0][tid] + reds[1][tid]);
        atomicAdd(&ssq[mhalf * 64 + tid], redq[0][tid] + redq[1][tid]);
    }
}

// bnpool2: PMN2 -> bn2+relu+pool -> xfrag
__global__ void k_bnpool2(const float* __restrict__ pmn2, const float* __restrict__ c2sum,
                          const float* __restrict__ c2ssq, const float* __restrict__ g2,
                          const float* __restrict__ b2, unsigned short* __restrict__ xfrag) {
    int i = blockIdx.x * 256 + threadIdx.x;    // 1048576
    int j    = i & 7;
    int lane = (i >> 3) & 63;
    int bt   = (i >> 9) & 31;
    int ks   = i >> 14;
    int b = bt * 16 + (lane & 15);
    int k = ks * 32 + (lane >> 4) * 8 + j;
    int c = k >> 4, psp = k & 15;
    float2 mm = *(const float2*)(&pmn2[((size_t)b * 2048 + c * 16 + psp) * 2]);
    float mean = c2sum[c] * (1.f / 32768.f);
    float var  = c2ssq[c] * (1.f / 32768.f) - mean * mean;
    float sc = g2[c] * rsqrtf(var + EPS);
    float sh = b2[c] - mean * sc;
    float v = (sc > 0.f) ? mm.x : mm.y;
    xfrag[i] = f2bf(fmaxf(0.f, fmaf(v, sc, sh)));
}

// fc1 MFMA: grid 256, wave = 1 f-tile; fused bn3 stats.
__global__ __launch_bounds__(256) void k_fc1(const unsigned short* __restrict__ xfrag,
                                             const unsigned short* __restrict__ wfrag,
                                             float* __restrict__ out,
                                             float* __restrict__ sum,
                                             float* __restrict__ ssq) {
    int lane = threadIdx.x & 63;
    int wave = threadIdx.x >> 6;
    int ft = (blockIdx.x & 7) * 4 + wave;      // f-tile 0..31
    int bT = blockIdx.x >> 3;                  // 0..31
    v4f acc = (v4f){0.f, 0.f, 0.f, 0.f};
    for (int ks = 0; ks < 64; ++ks) {
        v8s bfrag = *(const v8s*)(xfrag + ((size_t)(ks * 32 + bT) * 64 + lane) * 8);
        v8s afrag = *(const v8s*)(wfrag + ((size_t)(ks * 32 + ft) * 64 + lane) * 8);
        acc = __builtin_amdgcn_mfma_f32_16x16x32_bf16(afrag, bfrag, acc, 0, 0, 0);
    }
    int bb = bT * 16 + (lane & 15);
    int quad = lane >> 4;
    int f0 = ft * 16 + quad * 4;
    *(float4*)(&out[(size_t)bb * 512 + f0]) =
        make_float4(acc[0], acc[1], acc[2], acc[3]);
    #pragma unroll
    for (int r = 0; r < 4; ++r) {
        float s = acc[r], s2 = s * s;
        #pragma unroll
        for (int m = 1; m < 16; m <<= 1) { s += __shfl_xor(s, m); s2 += __shfl_xor(s2, m); }
        if ((lane & 15) == 0) { atomicAdd(&sum[f0 + r], s); atomicAdd(&ssq[f0 + r], s2); }
    }
}

// fc2 with inline bn3 finalize + relu: wave per batch row.
__global__ __launch_bounds__(256) void k_fc2(const float* __restrict__ x,
                                             const float* __restrict__ w,
                                             const float* __restrict__ bias,
                                             const float* __restrict__ fsum,
                                             const float* __restrict__ fssq,
                                             const float* __restrict__ g3,
                                             const float* __restrict__ b3,
                                             float* __restrict__ out) {
    int lane = threadIdx.x & 63;
    int b = blockIdx.x * 4 + (threadIdx.x >> 6);
    float xa[8], sm[8], sq[8], ga[8], ba[8];
    {
        const float4* p;
        p = (const float4*)(x + (size_t)b * 512 + lane * 8);
        *(float4*)xa = p[0]; *(float4*)(xa + 4) = p[1];
        p = (const float4*)(fsum + lane * 8);
        *(float4*)sm = p[0]; *(float4*)(sm + 4) = p[1];
        p = (const float4*)(fssq + lane * 8);
        *(float4*)sq = p[0]; *(float4*)(sq + 4) = p[1];
        p = (const float4*)(g3 + lane * 8);
        *(float4*)ga = p[0]; *(float4*)(ga + 4) = p[1];
        p = (const float4*)(b3 + lane * 8);
        *(float4*)ba = p[0]; *(float4*)(ba + 4) = p[1];
    }
    float h[8];
    #pragma unroll
    for (int e = 0; e < 8; ++e) {
        float mean = sm[e] * (1.f / 512.f);
        float var  = sq[e] * (1.f / 512.f) - mean * mean;
        float sc = ga[e] * rsqrtf(var + EPS);
        float sh = ba[e] - mean * sc;
        h[e] = fmaxf(0.f, fmaf(xa[e], sc, sh));
    }
    #pragma unroll
    for (int j = 0; j < 10; ++j) {
        const float4* wp = (const float4*)(w + j * 512 + lane * 8);
        float4 w0 = wp[0], w1 = wp[1];
        float p = h[0] * w0.x + h[1] * w0.y + h[2] * w0.z + h[3] * w0.w
                + h[4] * w1.x + h[5] * w1.y + h[6] * w1.z + h[7] * w1.w;
        #pragma unroll
        for (int o = 32; o; o >>= 1) p += __shfl_down(p, o);
        if (lane == 0) out[b * 10 + j] = p + bias[j];
    }
}

extern "C" void kernel_launch(void* const* d_in, const int* in_sizes, int n_in,
                              void* d_out, int out_size, void* d_ws, size_t ws_size,
                              hipStream_t stream) {
    const float* x       = (const float*)d_in[0];
    const float* conv1_w = (const float*)d_in[1];
    const float* bn1_g   = (const float*)d_in[3];
    const float* bn1_b   = (const float*)d_in[4];
    const float* conv2_w = (const float*)d_in[5];
    const float* bn2_g   = (const float*)d_in[7];
    const float* bn2_b   = (const float*)d_in[8];
    const float* fc1_w   = (const float*)d_in[9];
    const float* bn3_g   = (const float*)d_in[11];
    const float* bn3_b   = (const float*)d_in[12];
    const float* fc2_w   = (const float*)d_in[13];
    const float* fc2_b   = (const float*)d_in[14];
    // conv1_b / conv2_b / fc1_b are absorbed by train-mode BN

    float* wsf = (float*)d_ws;

    float* c1_sum = wsf + 16,   * c1_ssq = wsf + 80;
    float* c2_sum = wsf + 272,  * c2_ssq = wsf + 400;
    float* f_sum  = wsf + 1808, * f_ssq  = wsf + 2320;

    unsigned short* w2u = (unsigned short*)(wsf + W2F);
    float* wf2 = wsf + WF2F;
    unsigned short* wf1 = (unsigned short*)(wsf + WF1T);
    unsigned* PMN1 = (unsigned*)(wsf + A_F);         // [512][144][64] packed
    float* PMN2 = wsf + PMN2F;                       // [512][128][16][2]
    float* A    = wsf + A_F;                         // fc1out (PMN1 dead by then)
    unsigned short* xfrag = (unsigned short*)(wsf + B_F);

    // absmax partials + zero stats sums — one launch
    k_absz<<<390, 256, 0, stream>>>(conv1_w, conv2_w, fc1_w, fc2_w, wsf);

    // conv1 (inline c1 quant) + conv2/fc1/fc2 quant — one launch
    k_mid<<<869, 512, 0, stream>>>(x, conv1_w, conv2_w, fc1_w, fc2_w, wsf,
                                   PMN1, w2u, wf1, wf2);

    // conv2 MFMA: fused bn1 staging + counted-vmcnt 3-buffer pipeline
    k_conv2<<<1024, 256, 0, stream>>>(PMN1, w2u, c1_sum, c1_ssq, bn1_g, bn1_b,
                                      PMN2, c2_sum, c2_ssq);

    // bnpool2 -> xfrag
    k_bnpool2<<<4096, 256, 0, stream>>>(PMN2, c2_sum, c2_ssq, bn2_g, bn2_b, xfrag);

    // fc1 MFMA (grid 256, fused bn3 stats) -> A fp32 [512,512]
    k_fc1<<<256, 256, 0, stream>>>(xfrag, wf1, A, f_sum, f_ssq);

    // fc2 (inline bn3 finalize + relu) -> d_out [512,10]
    k_fc2<<<128, 256, 0, stream>>>(A, wf2, fc2_b, f_sum, f_ssq, bn3_g, bn3_b,
                                   (float*)d_out);
}

// Round 6
// 199.537 us; speedup vs baseline: 1.0561x; 1.0449x over previous
//
#include <hip/hip_runtime.h>
#include <stdint.h>

#define EPS 1e-5f

typedef short v8s __attribute__((ext_vector_type(8)));
typedef float v4f __attribute__((ext_vector_type(4)));

// ---------------- ws float layout ----------------
//  16/80    c1 sum/ssq (64 each)
//  272/400  c2 sum/ssq (128 each)
//  1024  absmax partial c1 (1)
//  1025  absmax partial f2 (1)
//  1040  absmax partials c2 (192)
//  1240  absmax partials f1 (190)
//  1808 fc sum(512) 2320 fc ssq(512)
//  W2F  = 8192    : conv2 weights bf16 MFMA-frag order (204800 us)
//  WF2F = 212992  : fc2 weights float [j][512]
//  A_F  = 262144  : PMN1 packed uint [512][144][64] ([262144,4980736));
//                   later fc1out fp32 [512,512] ([262144,524288), PMN1 dead)
//  PMN2F= 4980736 : PMN2 fp32 [512][128][16][2]
//  B_F  = 19136512: xfrag bf16 B-frag [2048][512]
//  WF1T = B_F + 1048576 : fc1 weights bf16 A-frag
static const size_t W2F   = 8192;
static const size_t WF2F  = 212992;
static const size_t A_F   = 262144;
static const size_t PMN2F = 4980736;
static const size_t B_F   = 19136512;
static const size_t WF1T  = B_F + 1048576;

#define P_C1 1024
#define P_F2 1025
#define P_C2 1040
#define P_F1 1240

__device__ inline unsigned short f2bf(float f) {
    unsigned u = __float_as_uint(f);
    return (unsigned short)((u + 0x7FFF + ((u >> 16) & 1)) >> 16);
}

// async global->LDS, 16B per lane
__device__ __forceinline__ void stage16(const unsigned short* g, unsigned short* l) {
    __builtin_amdgcn_global_load_lds(
        (const __attribute__((address_space(1))) unsigned int*)g,
        (__attribute__((address_space(3))) unsigned int*)l, 16, 0, 0);
}

// absmax partials (plain stores) + zero stats sums. grid 390 x 256.
__global__ void k_absz(const float* __restrict__ c1w, const float* __restrict__ c2w,
                       const float* __restrict__ f1w, const float* __restrict__ f2w,
                       float* __restrict__ wsf) {
    __shared__ float sm4[4];
    int blk = blockIdx.x;
    if (blk >= 384) {
        if (blk < 386) {
            int i = (blk - 384) * 256 + threadIdx.x + 16;
            if (i < 528) wsf[i] = 0.f;
        } else {
            int i = (blk - 386) * 256 + threadIdx.x + 1808;
            if (i < 2832) wsf[i] = 0.f;
        }
        return;
    }
    const float* w; int n; int nb; int bi; float* out;
    if (blk == 0)       { w = c1w; n = 1600;    nb = 1;   bi = 0;         out = wsf + P_C1; }
    else if (blk == 1)  { w = f2w; n = 5120;    nb = 1;   bi = 0;         out = wsf + P_F2; }
    else if (blk < 194) { w = c2w; n = 204800;  nb = 192; bi = blk - 2;   out = wsf + P_C2 + bi; }
    else                { w = f1w; n = 1048576; nb = 190; bi = blk - 194; out = wsf + P_F1 + bi; }
    float m = 0.f;
    for (int i = bi * 256 + threadIdx.x; i < n; i += nb * 256)
        m = fmaxf(m, fabsf(w[i]));
    #pragma unroll
    for (int o = 32; o; o >>= 1) m = fmaxf(m, __shfl_down(m, o));
    if ((threadIdx.x & 63) == 0) sm4[threadIdx.x >> 6] = m;
    __syncthreads();
    if (threadIdx.x == 0)
        *out = fmaxf(fmaxf(sm4[0], sm4[1]), fmaxf(sm4[2], sm4[3]));
}

// merged conv1 + ALL weight quant. grid 869 x 512.
__global__ __launch_bounds__(512) void k_mid(const float* __restrict__ x,
                                             const float* __restrict__ c1w,
                                             const float* __restrict__ c2w,
                                             const float* __restrict__ f1w,
                                             const float* __restrict__ f2w,
                                             float* __restrict__ wsf,
                                             unsigned* __restrict__ pmn1,
                                             unsigned short* __restrict__ w2u,
                                             unsigned short* __restrict__ wf1,
                                             float* __restrict__ wf2) {
    int blk = blockIdx.x;
    int tid = threadIdx.x;
    if (blk >= 512) {
        if (blk < 612) {
            float m = 0.f;
            for (int i = 0; i < 192; ++i) m = fmaxf(m, wsf[P_C2 + i]);
            float t = 0.05f * m;
            for (int i = (blk - 512) * 512 + tid; i < 204800; i += 100 * 512) {
                int j    = i & 7;
                int lane = (i >> 3) & 63;
                int mt   = (i >> 9) & 7;
                int ks   = (i >> 12) & 1;
                int p    = i >> 13;
                int c  = mt * 16 + (lane & 15);
                int ci = ks * 32 + (lane >> 4) * 8 + j;
                float v = c2w[c * 1600 + ci * 25 + p];
                w2u[i] = (v > t) ? (unsigned short)0x3F80
                                 : ((v < -t) ? (unsigned short)0xBF80 : (unsigned short)0);
            }
        } else if (blk < 868) {
            float m = 0.f;
            for (int i = 0; i < 190; ++i) m = fmaxf(m, wsf[P_F1 + i]);
            float t = 0.05f * m;
            for (int i = (blk - 612) * 512 + tid; i < 1048576; i += 256 * 512) {
                float v = f1w[i];
                unsigned short q = (v > t) ? (unsigned short)0x3F80
                                 : ((v < -t) ? (unsigned short)0xBF80 : (unsigned short)0);
                int f = i >> 11, k = i & 2047;
                int ft = f >> 4, fm = f & 15;
                int ks = k >> 5, kr = k & 31;
                int lane = (kr >> 3) * 16 + fm;
                wf1[((size_t)(ks * 32 + ft) * 64 + lane) * 8 + (kr & 7)] = q;
            }
        } else {
            float t = 0.05f * wsf[P_F2];
            for (int i = tid; i < 5120; i += 512) {
                float v = f2w[i];
                wf2[i] = (float)((v > t) - (v < -t));
            }
        }
        return;
    }
    // ---- conv1 ----
    __shared__ float xs[784];
    __shared__ float red[2][8][64];
    int b = blk;
    const float4* xim = (const float4*)(x + (size_t)b * 784);
    for (int i = tid; i < 196; i += 512) ((float4*)xs)[i] = xim[i];
    int c  = tid & 63;
    int wv = tid >> 6;
    float w[25];
    {
        float t = 0.05f * wsf[P_C1];
        const float* src = c1w + c * 25;
        #pragma unroll
        for (int k = 0; k < 25; ++k) {
            float v = src[k];
            w[k] = (float)((v > t) - (v < -t));
        }
    }
    __syncthreads();
    unsigned* ob = pmn1 + (size_t)b * 9216;
    float s = 0.f, s2 = 0.f;
    int ph = 0, pw = wv;
    for (int it = 0; it < 18; ++it) {
        const float* xp = xs + (ph * 2) * 28 + pw * 2;
        float win[36];
        #pragma unroll
        for (int i = 0; i < 6; ++i)
            #pragma unroll
            for (int j = 0; j < 3; ++j) {
                float2 t2 = *(const float2*)(xp + i * 28 + j * 2);
                win[i * 6 + j * 2] = t2.x; win[i * 6 + j * 2 + 1] = t2.y;
            }
        float v00 = 0.f, v01 = 0.f, v10 = 0.f, v11 = 0.f;
        #pragma unroll
        for (int i = 0; i < 5; ++i)
            #pragma unroll
            for (int j = 0; j < 5; ++j) {
                float wk = w[i * 5 + j];
                v00 = fmaf(win[i * 6 + j],           wk, v00);
                v01 = fmaf(win[i * 6 + j + 1],       wk, v01);
                v10 = fmaf(win[(i + 1) * 6 + j],     wk, v10);
                v11 = fmaf(win[(i + 1) * 6 + j + 1], wk, v11);
            }
        s  += v00 + v01 + v10 + v11;
        s2 += v00 * v00 + v01 * v01 + v10 * v10 + v11 * v11;
        float mx = fmaxf(fmaxf(v00, v01), fmaxf(v10, v11));
        float mn = fminf(fminf(v00, v01), fminf(v10, v11));
        ob[(ph * 12 + pw) * 64 + c] = ((unsigned)f2bf(mx) << 16) | (unsigned)f2bf(mn);
        pw += 8; if (pw >= 12) { pw -= 12; ++ph; }
    }
    red[0][wv][c] = s; red[1][wv][c] = s2;
    __syncthreads();
    if (tid < 64) {
        float S = 0.f, S2 = 0.f;
        #pragma unroll
        for (int i = 0; i < 8; ++i) { S += red[0][i][tid]; S2 += red[1][i][tid]; }
        atomicAdd(&wsf[16 + tid], S);
        atomicAdd(&wsf[80 + tid], S2);
    }
}

// conv2 MFMA v4: r3-EXACT step structure (double-buffer + __syncthreads,
// compiler-scheduled waits) but TWO images per block — 16 MFMA per step
// amortize the fixed per-step latency; weight staging shared by both images.
// grid 512 (= 256 img-pairs x 2 mhalf), LDS 61184B -> 2 blocks/CU resident.
__global__ __launch_bounds__(256) void k_conv2(const unsigned* __restrict__ pmn1,
                                               const unsigned short* __restrict__ wfrag,
                                               const float* __restrict__ c1sum,
                                               const float* __restrict__ c1ssq,
                                               const float* __restrict__ g1,
                                               const float* __restrict__ b1,
                                               float* __restrict__ pmn,
                                               float* __restrict__ sum,
                                               float* __restrict__ ssq) {
    __shared__ unsigned short xs[2][10944];    // 2 x [144][76] bf16 = 43776 B
    __shared__ unsigned short wb[2][4096];     // 2 x 8KB: one p = 2 ks x 4 mt
    __shared__ float reds[2][64], redq[2][64];
    int pair  = blockIdx.x >> 1;               // image pair 0..255
    int mhalf = blockIdx.x & 1;
    int tid  = threadIdx.x;
    int lane = tid & 63;
    int wave = tid >> 6;
    int nh = wave & 1, kp = wave >> 1;

    // bn1 finalize params for this thread's 4 fixed channels
    int ch0 = (tid & 15) * 4;
    float scv[4], shv[4];
    {
        const float invN = 1.f / 294912.f;
        #pragma unroll
        for (int j = 0; j < 4; ++j) {
            int ch = ch0 + j;
            float mean = c1sum[ch] * invN;
            float var  = c1ssq[ch] * invN - mean * mean;
            scv[j] = g1[ch] * rsqrtf(var + EPS);
            shv[j] = b1[ch] - mean * scv[j];
        }
    }
    // fused staging x2: PMN1 [144][64] packed -> bn1+relu+select -> xs bf16
    #pragma unroll
    for (int ii = 0; ii < 2; ++ii) {
        const uint4* srcp = (const uint4*)(pmn1 + (size_t)(pair * 2 + ii) * 9216);
        unsigned short* xsi = &xs[ii][0];
        for (int it = 0; it < 9; ++it) {
            int i = it * 256 + tid;            // uint4 index, 2304 per image
            int r = i >> 4;                    // row 0..143 (ch-group = tid&15)
            uint4 u4 = srcp[i];
            unsigned long long pack = 0;
            #pragma unroll
            for (int j = 0; j < 4; ++j) {
                unsigned u = (&u4.x)[j];
                float mx = __uint_as_float(u & 0xffff0000u);
                float mn = __uint_as_float(u << 16);
                float v = (scv[j] > 0.f) ? mx : mn;
                unsigned short o = f2bf(fmaxf(0.f, fmaf(v, scv[j], shv[j])));
                pack |= ((unsigned long long)o) << (16 * j);
            }
            *(unsigned long long*)(&xsi[r * 76 + ch0]) = pack;
        }
    }
    // prefetch p=0 weights (r3-exact)
    #pragma unroll
    for (int h = 0; h < 2; ++h) {
        int ksm = wave * 2 + h;
        int ks = ksm >> 2, mt = ksm & 3;
        const unsigned short* g = wfrag + (size_t)(ks * 8 + mhalf * 4 + mt) * 512 + lane * 8;
        stage16(g, &wb[0][ks * 2048 + mt * 512 + lane * 8]);
    }
    __syncthreads();

    int n = lane & 15, quad = lane >> 4;
    int ow = n & 7;
    int ohb0 = nh * 4 + (n >> 3);              // oh of bf0; bf1 = +2
    int col0 = kp * 32 + quad * 8;
    v4f acc[2][4][2];
    #pragma unroll
    for (int ii = 0; ii < 2; ++ii)
        #pragma unroll
        for (int mm = 0; mm < 4; ++mm) {
            acc[ii][mm][0] = (v4f){0,0,0,0};
            acc[ii][mm][1] = (v4f){0,0,0,0};
        }
    for (int p = 0; p < 25; ++p) {
        int cur = p & 1;
        if (p < 24) {
            #pragma unroll
            for (int h = 0; h < 2; ++h) {
                int ksm = wave * 2 + h;
                int ks = ksm >> 2, mt = ksm & 3;
                const unsigned short* g = wfrag +
                    (size_t)(((p + 1) * 2 + ks) * 8 + mhalf * 4 + mt) * 512 + lane * 8;
                stage16(g, &wb[cur ^ 1][ks * 2048 + mt * 512 + lane * 8]);
            }
        }
        int kh = p / 5, kw = p - (p / 5) * 5;
        int col = (ow + kw) * 76 + col0;
        v8s bfA0 = *(const v8s*)(&xs[0][(ohb0 + kh) * 912 + col]);   // 12*76=912
        v8s bfA1 = *(const v8s*)(&xs[0][(ohb0 + 2 + kh) * 912 + col]);
        v8s bfB0 = *(const v8s*)(&xs[1][(ohb0 + kh) * 912 + col]);
        v8s bfB1 = *(const v8s*)(&xs[1][(ohb0 + 2 + kh) * 912 + col]);
        #pragma unroll
        for (int mm = 0; mm < 4; ++mm) {
            v8s af = *(const v8s*)(&wb[cur][kp * 2048 + mm * 512 + lane * 8]);
            acc[0][mm][0] = __builtin_amdgcn_mfma_f32_16x16x32_bf16(af, bfA0, acc[0][mm][0], 0, 0, 0);
            acc[0][mm][1] = __builtin_amdgcn_mfma_f32_16x16x32_bf16(af, bfA1, acc[0][mm][1], 0, 0, 0);
            acc[1][mm][0] = __builtin_amdgcn_mfma_f32_16x16x32_bf16(af, bfB0, acc[1][mm][0], 0, 0, 0);
            acc[1][mm][1] = __builtin_amdgcn_mfma_f32_16x16x32_bf16(af, bfB1, acc[1][mm][1], 0, 0, 0);
        }
        __syncthreads();
    }
    // merge kp=1 partials into kp=0 via dead act-LDS (stride-36 float pad)
    float* mbuf = (float*)xs;                  // 2 x 18432 B <= 43776
    if (kp == 1) {
        #pragma unroll
        for (int ii = 0; ii < 2; ++ii) {
            float* d = mbuf + ii * 4608 + (nh * 64 + lane) * 36;
            #pragma unroll
            for (int mm = 0; mm < 4; ++mm) {
                *(v4f*)(d + mm * 8)     = acc[ii][mm][0];
                *(v4f*)(d + mm * 8 + 4) = acc[ii][mm][1];
            }
        }
    }
    __syncthreads();
    if (kp == 0) {
        #pragma unroll
        for (int ii = 0; ii < 2; ++ii) {
            const float* s = mbuf + ii * 4608 + (nh * 64 + lane) * 36;
            #pragma unroll
            for (int mm = 0; mm < 4; ++mm) {
                acc[ii][mm][0] += *(const v4f*)(s + mm * 8);
                acc[ii][mm][1] += *(const v4f*)(s + mm * 8 + 4);
            }
        }
        // epilogue: pooled {max,min} per image + per-channel stats (summed
        // over both images before the LDS/atomic reduction)
        float* po0 = pmn + (size_t)(pair * 2 + 0) * 4096;  // [128][16][2]
        float* po1 = pmn + (size_t)(pair * 2 + 1) * 4096;
        #pragma unroll
        for (int mm = 0; mm < 4; ++mm) {
            int cl0 = mm * 16 + quad * 4;
            #pragma unroll
            for (int r = 0; r < 4; ++r) {
                int cl = cl0 + r;
                int cc = mhalf * 64 + cl;
                float sA = 0.f, s2A = 0.f;
                #pragma unroll
                for (int ii = 0; ii < 2; ++ii) {
                    float* po = ii ? po1 : po0;
                    #pragma unroll
                    for (int bf = 0; bf < 2; ++bf) {
                        float v = acc[ii][mm][bf][r];
                        float pm = fmaxf(v, __shfl_xor(v, 1));
                        float pn = fminf(v, __shfl_xor(v, 1));
                        pm = fmaxf(pm, __shfl_xor(pm, 8));
                        pn = fminf(pn, __shfl_xor(pn, 8));
                        if (((n & 1) == 0) && (n < 8)) {
                            int psp = (nh * 2 + bf) * 4 + (n >> 1);
                            *(float2*)(&po[(cc * 16 + psp) * 2]) = make_float2(pm, pn);
                        }
                        float s = v, s2 = v * v;
                        #pragma unroll
                        for (int m = 1; m < 16; m <<= 1) { s += __shfl_xor(s, m); s2 += __shfl_xor(s2, m); }
                        sA += s; s2A += s2;
                    }
                }
                if (n == 0) { reds[nh][cl] = sA; redq[nh][cl] = s2A; }
            }
        }
    }
    __syncthreads();
    if (tid < 64) {
        atomicAdd(&sum[mhalf * 64 + tid], reds[0][tid] + reds[1][tid]);
        atomicAdd(&ssq[mhalf * 64 + tid], redq[0][tid] + redq[1][tid]);
    }
}

// bnpool2: PMN2 -> bn2+relu+pool -> xfrag
__global__ void k_bnpool2(const float* __restrict__ pmn2, const float* __restrict__ c2sum,
                          const float* __restrict__ c2ssq, const float* __restrict__ g2,
                          const float* __restrict__ b2, unsigned short* __restrict__ xfrag) {
    int i = blockIdx.x * 256 + threadIdx.x;    // 1048576
    int j    = i & 7;
    int lane = (i >> 3) & 63;
    int bt   = (i >> 9) & 31;
    int ks   = i >> 14;
    int b = bt * 16 + (lane & 15);
    int k = ks * 32 + (lane >> 4) * 8 + j;
    int c = k >> 4, psp = k & 15;
    float2 mm = *(const float2*)(&pmn2[((size_t)b * 2048 + c * 16 + psp) * 2]);
    float mean = c2sum[c] * (1.f / 32768.f);
    float var  = c2ssq[c] * (1.f / 32768.f) - mean * mean;
    float sc = g2[c] * rsqrtf(var + EPS);
    float sh = b2[c] - mean * sc;
    float v = (sc > 0.f) ? mm.x : mm.y;
    xfrag[i] = f2bf(fmaxf(0.f, fmaf(v, sc, sh)));
}

// fc1 MFMA: grid 256, wave = 1 f-tile; fused bn3 stats.
__global__ __launch_bounds__(256) void k_fc1(const unsigned short* __restrict__ xfrag,
                                             const unsigned short* __restrict__ wfrag,
                                             float* __restrict__ out,
                                             float* __restrict__ sum,
                                             float* __restrict__ ssq) {
    int lane = threadIdx.x & 63;
    int wave = threadIdx.x >> 6;
    int ft = (blockIdx.x & 7) * 4 + wave;      // f-tile 0..31
    int bT = blockIdx.x >> 3;                  // 0..31
    v4f acc = (v4f){0.f, 0.f, 0.f, 0.f};
    for (int ks = 0; ks < 64; ++ks) {
        v8s bfrag = *(const v8s*)(xfrag + ((size_t)(ks * 32 + bT) * 64 + lane) * 8);
        v8s afrag = *(const v8s*)(wfrag + ((size_t)(ks * 32 + ft) * 64 + lane) * 8);
        acc = __builtin_amdgcn_mfma_f32_16x16x32_bf16(afrag, bfrag, acc, 0, 0, 0);
    }
    int bb = bT * 16 + (lane & 15);
    int quad = lane >> 4;
    int f0 = ft * 16 + quad * 4;
    *(float4*)(&out[(size_t)bb * 512 + f0]) =
        make_float4(acc[0], acc[1], acc[2], acc[3]);
    #pragma unroll
    for (int r = 0; r < 4; ++r) {
        float s = acc[r], s2 = s * s;
        #pragma unroll
        for (int m = 1; m < 16; m <<= 1) { s += __shfl_xor(s, m); s2 += __shfl_xor(s2, m); }
        if ((lane & 15) == 0) { atomicAdd(&sum[f0 + r], s); atomicAdd(&ssq[f0 + r], s2); }
    }
}

// fc2 with inline bn3 finalize + relu: wave per batch row.
__global__ __launch_bounds__(256) void k_fc2(const float* __restrict__ x,
                                             const float* __restrict__ w,
                                             const float* __restrict__ bias,
                                             const float* __restrict__ fsum,
                                             const float* __restrict__ fssq,
                                             const float* __restrict__ g3,
                                             const float* __restrict__ b3,
                                             float* __restrict__ out) {
    int lane = threadIdx.x & 63;
    int b = blockIdx.x * 4 + (threadIdx.x >> 6);
    float xa[8], sm[8], sq[8], ga[8], ba[8];
    {
        const float4* p;
        p = (const float4*)(x + (size_t)b * 512 + lane * 8);
        *(float4*)xa = p[0]; *(float4*)(xa + 4) = p[1];
        p = (const float4*)(fsum + lane * 8);
        *(float4*)sm = p[0]; *(float4*)(sm + 4) = p[1];
        p = (const float4*)(fssq + lane * 8);
        *(float4*)sq = p[0]; *(float4*)(sq + 4) = p[1];
        p = (const float4*)(g3 + lane * 8);
        *(float4*)ga = p[0]; *(float4*)(ga + 4) = p[1];
        p = (const float4*)(b3 + lane * 8);
        *(float4*)ba = p[0]; *(float4*)(ba + 4) = p[1];
    }
    float h[8];
    #pragma unroll
    for (int e = 0; e < 8; ++e) {
        float mean = sm[e] * (1.f / 512.f);
        float var  = sq[e] * (1.f / 512.f) - mean * mean;
        float sc = ga[e] * rsqrtf(var + EPS);
        float sh = ba[e] - mean * sc;
        h[e] = fmaxf(0.f, fmaf(xa[e], sc, sh));
    }
    #pragma unroll
    for (int j = 0; j < 10; ++j) {
        const float4* wp = (const float4*)(w + j * 512 + lane * 8);
        float4 w0 = wp[0], w1 = wp[1];
        float p = h[0] * w0.x + h[1] * w0.y + h[2] * w0.z + h[3] * w0.w
                + h[4] * w1.x + h[5] * w1.y + h[6] * w1.z + h[7] * w1.w;
        #pragma unroll
        for (int o = 32; o; o >>= 1) p += __shfl_down(p, o);
        if (lane == 0) out[b * 10 + j] = p + bias[j];
    }
}

extern "C" void kernel_launch(void* const* d_in, const int* in_sizes, int n_in,
                              void* d_out, int out_size, void* d_ws, size_t ws_size,
                              hipStream_t stream) {
    const float* x       = (const float*)d_in[0];
    const float* conv1_w = (const float*)d_in[1];
    const float* bn1_g   = (const float*)d_in[3];
    const float* bn1_b   = (const float*)d_in[4];
    const float* conv2_w = (const float*)d_in[5];
    const float* bn2_g   = (const float*)d_in[7];
    const float* bn2_b   = (const float*)d_in[8];
    const float* fc1_w   = (const float*)d_in[9];
    const float* bn3_g   = (const float*)d_in[11];
    const float* bn3_b   = (const float*)d_in[12];
    const float* fc2_w   = (const float*)d_in[13];
    const float* fc2_b   = (const float*)d_in[14];
    // conv1_b / conv2_b / fc1_b are absorbed by train-mode BN

    float* wsf = (float*)d_ws;

    float* c1_sum = wsf + 16,   * c1_ssq = wsf + 80;
    float* c2_sum = wsf + 272,  * c2_ssq = wsf + 400;
    float* f_sum  = wsf + 1808, * f_ssq  = wsf + 2320;

    unsigned short* w2u = (unsigned short*)(wsf + W2F);
    float* wf2 = wsf + WF2F;
    unsigned short* wf1 = (unsigned short*)(wsf + WF1T);
    unsigned* PMN1 = (unsigned*)(wsf + A_F);         // [512][144][64] packed
    float* PMN2 = wsf + PMN2F;                       // [512][128][16][2]
    float* A    = wsf + A_F;                         // fc1out (PMN1 dead by then)
    unsigned short* xfrag = (unsigned short*)(wsf + B_F);

    // absmax partials + zero stats sums — one launch
    k_absz<<<390, 256, 0, stream>>>(conv1_w, conv2_w, fc1_w, fc2_w, wsf);

    // conv1 (inline c1 quant) + conv2/fc1/fc2 quant — one launch
    k_mid<<<869, 512, 0, stream>>>(x, conv1_w, conv2_w, fc1_w, fc2_w, wsf,
                                   PMN1, w2u, wf1, wf2);

    // conv2 MFMA: r3 step structure, 2 images/block (grid 512)
    k_conv2<<<512, 256, 0, stream>>>(PMN1, w2u, c1_sum, c1_ssq, bn1_g, bn1_b,
                                     PMN2, c2_sum, c2_ssq);

    // bnpool2 -> xfrag
    k_bnpool2<<<4096, 256, 0, stream>>>(PMN2, c2_sum, c2_ssq, bn2_g, bn2_b, xfrag);

    // fc1 MFMA (grid 256, fused bn3 stats) -> A fp32 [512,512]
    k_fc1<<<256, 256, 0, stream>>>(xfrag, wf1, A, f_sum, f_ssq);

    // fc2 (inline bn3 finalize + relu) -> d_out [512,10]
    k_fc2<<<128, 256, 0, stream>>>(A, wf2, fc2_b, f_sum, f_ssq, bn3_g, bn3_b,
                                   (float*)d_out);
}

// Round 7
// 187.082 us; speedup vs baseline: 1.1264x; 1.0666x over previous
//
#include <hip/hip_runtime.h>
#include <stdint.h>

#define EPS 1e-5f

typedef short v8s __attribute__((ext_vector_type(8)));
typedef float v4f __attribute__((ext_vector_type(4)));

// ---------------- ws float layout ----------------
//  16/80    c1 sum/ssq (64 each)
//  272/400  c2 sum/ssq (128 each)
//  1024  absmax partial c1 (1)
//  1025  absmax partial f2 (1)
//  1040  absmax partials c2 (192)
//  1240  absmax partials f1 (190)
//  1808 fc sum(512) 2320 fc ssq(512)
//  W2F  = 8192    : conv2 weights bf16 MFMA-frag order (204800 us)
//  WF2F = 212992  : fc2 weights float [j][512]
//  A_F  = 262144  : PMN1 packed uint [512][144][64] ([262144,4980736));
//                   later fc1out fp32 [512,512] ([262144,524288), PMN1 dead)
//  PMN2F= 4980736 : PMN2 fp32 [512][128][16][2]
//  B_F  = 19136512: xfrag bf16 B-frag [2048][512]
//  WF1T = B_F + 1048576 : fc1 weights bf16 A-frag
static const size_t W2F   = 8192;
static const size_t WF2F  = 212992;
static const size_t A_F   = 262144;
static const size_t PMN2F = 4980736;
static const size_t B_F   = 19136512;
static const size_t WF1T  = B_F + 1048576;

#define P_C1 1024
#define P_F2 1025
#define P_C2 1040
#define P_F1 1240

__device__ inline unsigned short f2bf(float f) {
    unsigned u = __float_as_uint(f);
    return (unsigned short)((u + 0x7FFF + ((u >> 16) & 1)) >> 16);
}

// async global->LDS, 16B per lane
__device__ __forceinline__ void stage16(const unsigned short* g, unsigned short* l) {
    __builtin_amdgcn_global_load_lds(
        (const __attribute__((address_space(1))) unsigned int*)g,
        (__attribute__((address_space(3))) unsigned int*)l, 16, 0, 0);
}

// absmax partials (plain stores) + zero stats sums. grid 390 x 256.
__global__ void k_absz(const float* __restrict__ c1w, const float* __restrict__ c2w,
                       const float* __restrict__ f1w, const float* __restrict__ f2w,
                       float* __restrict__ wsf) {
    __shared__ float sm4[4];
    int blk = blockIdx.x;
    if (blk >= 384) {
        if (blk < 386) {
            int i = (blk - 384) * 256 + threadIdx.x + 16;
            if (i < 528) wsf[i] = 0.f;
        } else {
            int i = (blk - 386) * 256 + threadIdx.x + 1808;
            if (i < 2832) wsf[i] = 0.f;
        }
        return;
    }
    const float* w; int n; int nb; int bi; float* out;
    if (blk == 0)       { w = c1w; n = 1600;    nb = 1;   bi = 0;         out = wsf + P_C1; }
    else if (blk == 1)  { w = f2w; n = 5120;    nb = 1;   bi = 0;         out = wsf + P_F2; }
    else if (blk < 194) { w = c2w; n = 204800;  nb = 192; bi = blk - 2;   out = wsf + P_C2 + bi; }
    else                { w = f1w; n = 1048576; nb = 190; bi = blk - 194; out = wsf + P_F1 + bi; }
    float m = 0.f;
    for (int i = bi * 256 + threadIdx.x; i < n; i += nb * 256)
        m = fmaxf(m, fabsf(w[i]));
    #pragma unroll
    for (int o = 32; o; o >>= 1) m = fmaxf(m, __shfl_down(m, o));
    if ((threadIdx.x & 63) == 0) sm4[threadIdx.x >> 6] = m;
    __syncthreads();
    if (threadIdx.x == 0)
        *out = fmaxf(fmaxf(sm4[0], sm4[1]), fmaxf(sm4[2], sm4[3]));
}

// merged conv1 + ALL weight quant. grid 1381 x 512:
//   [0,1024)     : conv1, 2 blocks/image (half = 6 pool rows), 9 iters/thread
//   [1024,1124)  : conv2 bf16 A-frag quant (grid-stride)
//   [1124,1380)  : fc1 bf16 A-frag quant (grid-stride)
//   1380         : fc2 float quant
__global__ __launch_bounds__(512) void k_mid(const float* __restrict__ x,
                                             const float* __restrict__ c1w,
                                             const float* __restrict__ c2w,
                                             const float* __restrict__ f1w,
                                             const float* __restrict__ f2w,
                                             float* __restrict__ wsf,
                                             unsigned* __restrict__ pmn1,
                                             unsigned short* __restrict__ w2u,
                                             unsigned short* __restrict__ wf1,
                                             float* __restrict__ wf2) {
    int blk = blockIdx.x;
    int tid = threadIdx.x;
    if (blk >= 1024) {
        if (blk < 1124) {
            // conv2 quant: threshold via parallel reduce of 192 partials
            __shared__ float rm[8];
            float m = (tid < 192) ? wsf[P_C2 + tid] : 0.f;
            #pragma unroll
            for (int o = 32; o; o >>= 1) m = fmaxf(m, __shfl_down(m, o));
            if ((tid & 63) == 0) rm[tid >> 6] = m;
            __syncthreads();
            float t = 0.05f * fmaxf(fmaxf(rm[0], rm[1]), rm[2]);
            for (int i = (blk - 1024) * 512 + tid; i < 204800; i += 100 * 512) {
                int j    = i & 7;
                int lane = (i >> 3) & 63;
                int mt   = (i >> 9) & 7;
                int ks   = (i >> 12) & 1;
                int p    = i >> 13;
                int c  = mt * 16 + (lane & 15);
                int ci = ks * 32 + (lane >> 4) * 8 + j;
                float v = c2w[c * 1600 + ci * 25 + p];
                w2u[i] = (v > t) ? (unsigned short)0x3F80
                                 : ((v < -t) ? (unsigned short)0xBF80 : (unsigned short)0);
            }
        } else if (blk < 1380) {
            // fc1 quant: threshold via parallel reduce of 190 partials
            __shared__ float rm[8];
            float m = (tid < 190) ? wsf[P_F1 + tid] : 0.f;
            #pragma unroll
            for (int o = 32; o; o >>= 1) m = fmaxf(m, __shfl_down(m, o));
            if ((tid & 63) == 0) rm[tid >> 6] = m;
            __syncthreads();
            float t = 0.05f * fmaxf(fmaxf(rm[0], rm[1]), rm[2]);
            for (int i = (blk - 1124) * 512 + tid; i < 1048576; i += 256 * 512) {
                float v = f1w[i];
                unsigned short q = (v > t) ? (unsigned short)0x3F80
                                 : ((v < -t) ? (unsigned short)0xBF80 : (unsigned short)0);
                int f = i >> 11, k = i & 2047;
                int ft = f >> 4, fm = f & 15;
                int ks = k >> 5, kr = k & 31;
                int lane = (kr >> 3) * 16 + fm;
                wf1[((size_t)(ks * 32 + ft) * 64 + lane) * 8 + (kr & 7)] = q;
            }
        } else {
            float t = 0.05f * wsf[P_F2];
            for (int i = tid; i < 5120; i += 512) {
                float v = f2w[i];
                wf2[i] = (float)((v > t) - (v < -t));
            }
        }
        return;
    }
    // ---- conv1: 2 blocks per image, each owns 6 pool rows (72 windows) ----
    __shared__ float xs[448];                  // 16 rows x 28
    __shared__ float red[2][8][64];
    int img  = blk >> 1;
    int half = blk & 1;
    const float4* xim = (const float4*)(x + (size_t)img * 784 + half * 336);
    for (int i = tid; i < 112; i += 512) ((float4*)xs)[i] = xim[i];
    int c  = tid & 63;
    int wv = tid >> 6;
    float w[25];
    {
        float t = 0.05f * wsf[P_C1];
        const float* src = c1w + c * 25;
        #pragma unroll
        for (int k = 0; k < 25; ++k) {
            float v = src[k];
            w[k] = (float)((v > t) - (v < -t));
        }
    }
    __syncthreads();
    unsigned* ob = pmn1 + (size_t)img * 9216;
    float s = 0.f, s2 = 0.f;
    int lph = 0, pw = wv;
    for (int it = 0; it < 9; ++it) {
        const float* xp = xs + (lph * 2) * 28 + pw * 2;
        float win[36];
        #pragma unroll
        for (int i = 0; i < 6; ++i)
            #pragma unroll
            for (int j = 0; j < 3; ++j) {
                float2 t2 = *(const float2*)(xp + i * 28 + j * 2);
                win[i * 6 + j * 2] = t2.x; win[i * 6 + j * 2 + 1] = t2.y;
            }
        float v00 = 0.f, v01 = 0.f, v10 = 0.f, v11 = 0.f;
        #pragma unroll
        for (int i = 0; i < 5; ++i)
            #pragma unroll
            for (int j = 0; j < 5; ++j) {
                float wk = w[i * 5 + j];
                v00 = fmaf(win[i * 6 + j],           wk, v00);
                v01 = fmaf(win[i * 6 + j + 1],       wk, v01);
                v10 = fmaf(win[(i + 1) * 6 + j],     wk, v10);
                v11 = fmaf(win[(i + 1) * 6 + j + 1], wk, v11);
            }
        s  += v00 + v01 + v10 + v11;
        s2 += v00 * v00 + v01 * v01 + v10 * v10 + v11 * v11;
        float mx = fmaxf(fmaxf(v00, v01), fmaxf(v10, v11));
        float mn = fminf(fminf(v00, v01), fminf(v10, v11));
        ob[((half * 6 + lph) * 12 + pw) * 64 + c] = ((unsigned)f2bf(mx) << 16) | (unsigned)f2bf(mn);
        pw += 8; if (pw >= 12) { pw -= 12; ++lph; }
    }
    red[0][wv][c] = s; red[1][wv][c] = s2;
    __syncthreads();
    if (tid < 64) {
        float S = 0.f, S2 = 0.f;
        #pragma unroll
        for (int i = 0; i < 8; ++i) { S += red[0][i][tid]; S2 += red[1][i][tid]; }
        atomicAdd(&wsf[16 + tid], S);
        atomicAdd(&wsf[80 + tid], S2);
    }
}

// conv2 MFMA v4: r3 step structure, TWO images per block (r6 winner, unchanged)
__global__ __launch_bounds__(256) void k_conv2(const unsigned* __restrict__ pmn1,
                                               const unsigned short* __restrict__ wfrag,
                                               const float* __restrict__ c1sum,
                                               const float* __restrict__ c1ssq,
                                               const float* __restrict__ g1,
                                               const float* __restrict__ b1,
                                               float* __restrict__ pmn,
                                               float* __restrict__ sum,
                                               float* __restrict__ ssq) {
    __shared__ unsigned short xs[2][10944];    // 2 x [144][76] bf16 = 43776 B
    __shared__ unsigned short wb[2][4096];     // 2 x 8KB: one p = 2 ks x 4 mt
    __shared__ float reds[2][64], redq[2][64];
    int pair  = blockIdx.x >> 1;               // image pair 0..255
    int mhalf = blockIdx.x & 1;
    int tid  = threadIdx.x;
    int lane = tid & 63;
    int wave = tid >> 6;
    int nh = wave & 1, kp = wave >> 1;

    // bn1 finalize params for this thread's 4 fixed channels
    int ch0 = (tid & 15) * 4;
    float scv[4], shv[4];
    {
        const float invN = 1.f / 294912.f;
        #pragma unroll
        for (int j = 0; j < 4; ++j) {
            int ch = ch0 + j;
            float mean = c1sum[ch] * invN;
            float var  = c1ssq[ch] * invN - mean * mean;
            scv[j] = g1[ch] * rsqrtf(var + EPS);
            shv[j] = b1[ch] - mean * scv[j];
        }
    }
    // fused staging x2: PMN1 [144][64] packed -> bn1+relu+select -> xs bf16
    #pragma unroll
    for (int ii = 0; ii < 2; ++ii) {
        const uint4* srcp = (const uint4*)(pmn1 + (size_t)(pair * 2 + ii) * 9216);
        unsigned short* xsi = &xs[ii][0];
        for (int it = 0; it < 9; ++it) {
            int i = it * 256 + tid;            // uint4 index, 2304 per image
            int r = i >> 4;                    // row 0..143 (ch-group = tid&15)
            uint4 u4 = srcp[i];
            unsigned long long pack = 0;
            #pragma unroll
            for (int j = 0; j < 4; ++j) {
                unsigned u = (&u4.x)[j];
                float mx = __uint_as_float(u & 0xffff0000u);
                float mn = __uint_as_float(u << 16);
                float v = (scv[j] > 0.f) ? mx : mn;
                unsigned short o = f2bf(fmaxf(0.f, fmaf(v, scv[j], shv[j])));
                pack |= ((unsigned long long)o) << (16 * j);
            }
            *(unsigned long long*)(&xsi[r * 76 + ch0]) = pack;
        }
    }
    // prefetch p=0 weights
    #pragma unroll
    for (int h = 0; h < 2; ++h) {
        int ksm = wave * 2 + h;
        int ks = ksm >> 2, mt = ksm & 3;
        const unsigned short* g = wfrag + (size_t)(ks * 8 + mhalf * 4 + mt) * 512 + lane * 8;
        stage16(g, &wb[0][ks * 2048 + mt * 512 + lane * 8]);
    }
    __syncthreads();

    int n = lane & 15, quad = lane >> 4;
    int ow = n & 7;
    int ohb0 = nh * 4 + (n >> 3);              // oh of bf0; bf1 = +2
    int col0 = kp * 32 + quad * 8;
    v4f acc[2][4][2];
    #pragma unroll
    for (int ii = 0; ii < 2; ++ii)
        #pragma unroll
        for (int mm = 0; mm < 4; ++mm) {
            acc[ii][mm][0] = (v4f){0,0,0,0};
            acc[ii][mm][1] = (v4f){0,0,0,0};
        }
    for (int p = 0; p < 25; ++p) {
        int cur = p & 1;
        if (p < 24) {
            #pragma unroll
            for (int h = 0; h < 2; ++h) {
                int ksm = wave * 2 + h;
                int ks = ksm >> 2, mt = ksm & 3;
                const unsigned short* g = wfrag +
                    (size_t)(((p + 1) * 2 + ks) * 8 + mhalf * 4 + mt) * 512 + lane * 8;
                stage16(g, &wb[cur ^ 1][ks * 2048 + mt * 512 + lane * 8]);
            }
        }
        int kh = p / 5, kw = p - (p / 5) * 5;
        int col = (ow + kw) * 76 + col0;
        v8s bfA0 = *(const v8s*)(&xs[0][(ohb0 + kh) * 912 + col]);   // 12*76=912
        v8s bfA1 = *(const v8s*)(&xs[0][(ohb0 + 2 + kh) * 912 + col]);
        v8s bfB0 = *(const v8s*)(&xs[1][(ohb0 + kh) * 912 + col]);
        v8s bfB1 = *(const v8s*)(&xs[1][(ohb0 + 2 + kh) * 912 + col]);
        #pragma unroll
        for (int mm = 0; mm < 4; ++mm) {
            v8s af = *(const v8s*)(&wb[cur][kp * 2048 + mm * 512 + lane * 8]);
            acc[0][mm][0] = __builtin_amdgcn_mfma_f32_16x16x32_bf16(af, bfA0, acc[0][mm][0], 0, 0, 0);
            acc[0][mm][1] = __builtin_amdgcn_mfma_f32_16x16x32_bf16(af, bfA1, acc[0][mm][1], 0, 0, 0);
            acc[1][mm][0] = __builtin_amdgcn_mfma_f32_16x16x32_bf16(af, bfB0, acc[1][mm][0], 0, 0, 0);
            acc[1][mm][1] = __builtin_amdgcn_mfma_f32_16x16x32_bf16(af, bfB1, acc[1][mm][1], 0, 0, 0);
        }
        __syncthreads();
    }
    // merge kp=1 partials into kp=0 via dead act-LDS (stride-36 float pad)
    float* mbuf = (float*)xs;                  // 2 x 18432 B <= 43776
    if (kp == 1) {
        #pragma unroll
        for (int ii = 0; ii < 2; ++ii) {
            float* d = mbuf + ii * 4608 + (nh * 64 + lane) * 36;
            #pragma unroll
            for (int mm = 0; mm < 4; ++mm) {
                *(v4f*)(d + mm * 8)     = acc[ii][mm][0];
                *(v4f*)(d + mm * 8 + 4) = acc[ii][mm][1];
            }
        }
    }
    __syncthreads();
    if (kp == 0) {
        #pragma unroll
        for (int ii = 0; ii < 2; ++ii) {
            const float* s = mbuf + ii * 4608 + (nh * 64 + lane) * 36;
            #pragma unroll
            for (int mm = 0; mm < 4; ++mm) {
                acc[ii][mm][0] += *(const v4f*)(s + mm * 8);
                acc[ii][mm][1] += *(const v4f*)(s + mm * 8 + 4);
            }
        }
        float* po0 = pmn + (size_t)(pair * 2 + 0) * 4096;  // [128][16][2]
        float* po1 = pmn + (size_t)(pair * 2 + 1) * 4096;
        #pragma unroll
        for (int mm = 0; mm < 4; ++mm) {
            int cl0 = mm * 16 + quad * 4;
            #pragma unroll
            for (int r = 0; r < 4; ++r) {
                int cl = cl0 + r;
                int cc = mhalf * 64 + cl;
                float sA = 0.f, s2A = 0.f;
                #pragma unroll
                for (int ii = 0; ii < 2; ++ii) {
                    float* po = ii ? po1 : po0;
                    #pragma unroll
                    for (int bf = 0; bf < 2; ++bf) {
                        float v = acc[ii][mm][bf][r];
                        float pm = fmaxf(v, __shfl_xor(v, 1));
                        float pn = fminf(v, __shfl_xor(v, 1));
                        pm = fmaxf(pm, __shfl_xor(pm, 8));
                        pn = fminf(pn, __shfl_xor(pn, 8));
                        if (((n & 1) == 0) && (n < 8)) {
                            int psp = (nh * 2 + bf) * 4 + (n >> 1);
                            *(float2*)(&po[(cc * 16 + psp) * 2]) = make_float2(pm, pn);
                        }
                        float s = v, s2 = v * v;
                        #pragma unroll
                        for (int m = 1; m < 16; m <<= 1) { s += __shfl_xor(s, m); s2 += __shfl_xor(s2, m); }
                        sA += s; s2A += s2;
                    }
                }
                if (n == 0) { reds[nh][cl] = sA; redq[nh][cl] = s2A; }
            }
        }
    }
    __syncthreads();
    if (tid < 64) {
        atomicAdd(&sum[mhalf * 64 + tid], reds[0][tid] + reds[1][tid]);
        atomicAdd(&ssq[mhalf * 64 + tid], redq[0][tid] + redq[1][tid]);
    }
}

// bnpool2: PMN2 -> bn2+relu+pool -> xfrag
__global__ void k_bnpool2(const float* __restrict__ pmn2, const float* __restrict__ c2sum,
                          const float* __restrict__ c2ssq, const float* __restrict__ g2,
                          const float* __restrict__ b2, unsigned short* __restrict__ xfrag) {
    int i = blockIdx.x * 256 + threadIdx.x;    // 1048576
    int j    = i & 7;
    int lane = (i >> 3) & 63;
    int bt   = (i >> 9) & 31;
    int ks   = i >> 14;
    int b = bt * 16 + (lane & 15);
    int k = ks * 32 + (lane >> 4) * 8 + j;
    int c = k >> 4, psp = k & 15;
    float2 mm = *(const float2*)(&pmn2[((size_t)b * 2048 + c * 16 + psp) * 2]);
    float mean = c2sum[c] * (1.f / 32768.f);
    float var  = c2ssq[c] * (1.f / 32768.f) - mean * mean;
    float sc = g2[c] * rsqrtf(var + EPS);
    float sh = b2[c] - mean * sc;
    float v = (sc > 0.f) ? mm.x : mm.y;
    xfrag[i] = f2bf(fmaxf(0.f, fmaf(v, sc, sh)));
}

// fc1 MFMA: grid 256, wave = 1 f-tile; fused bn3 stats.
__global__ __launch_bounds__(256) void k_fc1(const unsigned short* __restrict__ xfrag,
                                             const unsigned short* __restrict__ wfrag,
                                             float* __restrict__ out,
                                             float* __restrict__ sum,
                                             float* __restrict__ ssq) {
    int lane = threadIdx.x & 63;
    int wave = threadIdx.x >> 6;
    int ft = (blockIdx.x & 7) * 4 + wave;      // f-tile 0..31
    int bT = blockIdx.x >> 3;                  // 0..31
    v4f acc = (v4f){0.f, 0.f, 0.f, 0.f};
    for (int ks = 0; ks < 64; ++ks) {
        v8s bfrag = *(const v8s*)(xfrag + ((size_t)(ks * 32 + bT) * 64 + lane) * 8);
        v8s afrag = *(const v8s*)(wfrag + ((size_t)(ks * 32 + ft) * 64 + lane) * 8);
        acc = __builtin_amdgcn_mfma_f32_16x16x32_bf16(afrag, bfrag, acc, 0, 0, 0);
    }
    int bb = bT * 16 + (lane & 15);
    int quad = lane >> 4;
    int f0 = ft * 16 + quad * 4;
    *(float4*)(&out[(size_t)bb * 512 + f0]) =
        make_float4(acc[0], acc[1], acc[2], acc[3]);
    #pragma unroll
    for (int r = 0; r < 4; ++r) {
        float s = acc[r], s2 = s * s;
        #pragma unroll
        for (int m = 1; m < 16; m <<= 1) { s += __shfl_xor(s, m); s2 += __shfl_xor(s2, m); }
        if ((lane & 15) == 0) { atomicAdd(&sum[f0 + r], s); atomicAdd(&ssq[f0 + r], s2); }
    }
}

// fc2 with inline bn3 finalize + relu: wave per batch row.
__global__ __launch_bounds__(256) void k_fc2(const float* __restrict__ x,
                                             const float* __restrict__ w,
                                             const float* __restrict__ bias,
                                             const float* __restrict__ fsum,
                                             const float* __restrict__ fssq,
                                             const float* __restrict__ g3,
                                             const float* __restrict__ b3,
                                             float* __restrict__ out) {
    int lane = threadIdx.x & 63;
    int b = blockIdx.x * 4 + (threadIdx.x >> 6);
    float xa[8], sm[8], sq[8], ga[8], ba[8];
    {
        const float4* p;
        p = (const float4*)(x + (size_t)b * 512 + lane * 8);
        *(float4*)xa = p[0]; *(float4*)(xa + 4) = p[1];
        p = (const float4*)(fsum + lane * 8);
        *(float4*)sm = p[0]; *(float4*)(sm + 4) = p[1];
        p = (const float4*)(fssq + lane * 8);
        *(float4*)sq = p[0]; *(float4*)(sq + 4) = p[1];
        p = (const float4*)(g3 + lane * 8);
        *(float4*)ga = p[0]; *(float4*)(ga + 4) = p[1];
        p = (const float4*)(b3 + lane * 8);
        *(float4*)ba = p[0]; *(float4*)(ba + 4) = p[1];
    }
    float h[8];
    #pragma unroll
    for (int e = 0; e < 8; ++e) {
        float mean = sm[e] * (1.f / 512.f);
        float var  = sq[e] * (1.f / 512.f) - mean * mean;
        float sc = ga[e] * rsqrtf(var + EPS);
        float sh = ba[e] - mean * sc;
        h[e] = fmaxf(0.f, fmaf(xa[e], sc, sh));
    }
    #pragma unroll
    for (int j = 0; j < 10; ++j) {
        const float4* wp = (const float4*)(w + j * 512 + lane * 8);
        float4 w0 = wp[0], w1 = wp[1];
        float p = h[0] * w0.x + h[1] * w0.y + h[2] * w0.z + h[3] * w0.w
                + h[4] * w1.x + h[5] * w1.y + h[6] * w1.z + h[7] * w1.w;
        #pragma unroll
        for (int o = 32; o; o >>= 1) p += __shfl_down(p, o);
        if (lane == 0) out[b * 10 + j] = p + bias[j];
    }
}

extern "C" void kernel_launch(void* const* d_in, const int* in_sizes, int n_in,
                              void* d_out, int out_size, void* d_ws, size_t ws_size,
                              hipStream_t stream) {
    const float* x       = (const float*)d_in[0];
    const float* conv1_w = (const float*)d_in[1];
    const float* bn1_g   = (const float*)d_in[3];
    const float* bn1_b   = (const float*)d_in[4];
    const float* conv2_w = (const float*)d_in[5];
    const float* bn2_g   = (const float*)d_in[7];
    const float* bn2_b   = (const float*)d_in[8];
    const float* fc1_w   = (const float*)d_in[9];
    const float* bn3_g   = (const float*)d_in[11];
    const float* bn3_b   = (const float*)d_in[12];
    const float* fc2_w   = (const float*)d_in[13];
    const float* fc2_b   = (const float*)d_in[14];
    // conv1_b / conv2_b / fc1_b are absorbed by train-mode BN

    float* wsf = (float*)d_ws;

    float* c1_sum = wsf + 16,   * c1_ssq = wsf + 80;
    float* c2_sum = wsf + 272,  * c2_ssq = wsf + 400;
    float* f_sum  = wsf + 1808, * f_ssq  = wsf + 2320;

    unsigned short* w2u = (unsigned short*)(wsf + W2F);
    float* wf2 = wsf + WF2F;
    unsigned short* wf1 = (unsigned short*)(wsf + WF1T);
    unsigned* PMN1 = (unsigned*)(wsf + A_F);         // [512][144][64] packed
    float* PMN2 = wsf + PMN2F;                       // [512][128][16][2]
    float* A    = wsf + A_F;                         // fc1out (PMN1 dead by then)
    unsigned short* xfrag = (unsigned short*)(wsf + B_F);

    // absmax partials + zero stats sums — one launch
    k_absz<<<390, 256, 0, stream>>>(conv1_w, conv2_w, fc1_w, fc2_w, wsf);

    // conv1 (2 blocks/image) + conv2/fc1/fc2 quant — one launch, grid 1381
    k_mid<<<1381, 512, 0, stream>>>(x, conv1_w, conv2_w, fc1_w, fc2_w, wsf,
                                    PMN1, w2u, wf1, wf2);

    // conv2 MFMA: r3 step structure, 2 images/block (grid 512)
    k_conv2<<<512, 256, 0, stream>>>(PMN1, w2u, c1_sum, c1_ssq, bn1_g, bn1_b,
                                     PMN2, c2_sum, c2_ssq);

    // bnpool2 -> xfrag
    k_bnpool2<<<4096, 256, 0, stream>>>(PMN2, c2_sum, c2_ssq, bn2_g, bn2_b, xfrag);

    // fc1 MFMA (grid 256, fused bn3 stats) -> A fp32 [512,512]
    k_fc1<<<256, 256, 0, stream>>>(xfrag, wf1, A, f_sum, f_ssq);

    // fc2 (inline bn3 finalize + relu) -> d_out [512,10]
    k_fc2<<<128, 256, 0, stream>>>(A, wf2, fc2_b, f_sum, f_ssq, bn3_g, bn3_b,
                                   (float*)d_out);
}